// Round 14
// baseline (269.799 us; speedup 1.0000x reference)
//
#include <hip/hip_runtime.h>
#include <cstdint>
#include <cmath>

#define DH 64
#define SQB 2048
#define SKVB 1024
#define DE 512

typedef _Float16 f16;
typedef _Float16 f16x8 __attribute__((ext_vector_type(8)));
typedef float f32x4 __attribute__((ext_vector_type(4)));
typedef float f32x16 __attribute__((ext_vector_type(16)));
typedef unsigned int u32;

#define MFMA32(A, B, C) __builtin_amdgcn_mfma_f32_32x32x16_f16(A, B, C, 0, 0, 0)

// ---------------------------------------------------------------------------
// async global->LDS 16B (wave-uniform LDS base + lane*16; global addr per-lane)
// ---------------------------------------------------------------------------
__device__ __forceinline__ void gl16(const f16* g, f16* l) {
  __builtin_amdgcn_global_load_lds(
      (const __attribute__((address_space(1))) u32*)g,
      (__attribute__((address_space(3))) u32*)l, 16, 0, 0);
}

// ---------------------------------------------------------------------------
// split helpers
// ---------------------------------------------------------------------------
__device__ __forceinline__ void do_split(const float* __restrict__ in,
                                         f16* __restrict__ hi, f16* __restrict__ lo,
                                         int i, float scale) {
  float4 v = ((const float4*)in)[i];
  v.x *= scale; v.y *= scale; v.z *= scale; v.w *= scale;
  f16 h0 = (f16)v.x, h1 = (f16)v.y, h2 = (f16)v.z, h3 = (f16)v.w;
  f16 l0 = (f16)(v.x - (float)h0), l1 = (f16)(v.y - (float)h1);
  f16 l2 = (f16)(v.z - (float)h2), l3 = (f16)(v.w - (float)h3);
  f16 hb[4] = {h0, h1, h2, h3};
  f16 lb[4] = {l0, l1, l2, l3};
  ((uint2*)hi)[i] = *(const uint2*)hb;
  ((uint2*)lo)[i] = *(const uint2*)lb;
}

// x + y in one launch (scale 1.0 both)
__global__ __launch_bounds__(256)
void split2(const float* __restrict__ a, f16* __restrict__ ah, f16* __restrict__ al, int na,
            const float* __restrict__ b, f16* __restrict__ bh, f16* __restrict__ bl, int nb) {
  const int i = blockIdx.x * 256 + threadIdx.x;
  if (i < na) do_split(a, ah, al, i, 1.0f);
  else if (i < na + nb) do_split(b, bh, bl, i - na, 1.0f);
}

// all four weights in one launch
__global__ __launch_bounds__(256)
void split4(const float* __restrict__ a, f16* __restrict__ ah, f16* __restrict__ al, int na, float sa,
            const float* __restrict__ b, f16* __restrict__ bh, f16* __restrict__ bl, int nb, float sb,
            const float* __restrict__ c, f16* __restrict__ ch, f16* __restrict__ cl, int nc, float sc,
            const float* __restrict__ d, f16* __restrict__ dh, f16* __restrict__ dl, int nd, float sd) {
  int i = blockIdx.x * 256 + threadIdx.x;
  if (i < na) { do_split(a, ah, al, i, sa); return; }
  i -= na;
  if (i < nb) { do_split(b, bh, bl, i, sb); return; }
  i -= nb;
  if (i < nc) { do_split(c, ch, cl, i, sc); return; }
  i -= nc;
  if (i < nd) do_split(d, dh, dl, i, sd);
}

// ---------------------------------------------------------------------------
// MFMA f16 GEMM — R4-validated math, global_load_lds(16) staging with
// pre-swizzled global source. Double-buffered, one barrier per K-step.
// NSPLIT=1 kernels (32KB LDS) run at 4 blocks/CU; NSPLIT=3 (64KB) at 2.
// OUT=0: C fp32. OUT=1: split-f16 pair of (C * oscale).
// ---------------------------------------------------------------------------
template <int NSPLIT, int OUT>
__global__ __launch_bounds__(256, NSPLIT == 3 ? 2 : 4)
void gemm_f16(const f16* __restrict__ Ah, const f16* __restrict__ Al,
              const f16* __restrict__ Wh, const f16* __restrict__ Wl,
              const float* __restrict__ bias, float* __restrict__ C,
              f16* __restrict__ Ch, f16* __restrict__ Cl,
              int M, int N, int K, float inv, float oscale) {
  constexpr int NPART = (NSPLIT == 3) ? 4 : 2;
  __shared__ f16 smem[2][NPART * 4096];   // parts: As, Ws, (Als, Wls)

  const int tid = threadIdx.x;
  const int w = tid >> 6;
  const int l = tid & 63;
  const int wm = w >> 1, wn = w & 1;
  const int m0 = blockIdx.y * 128;
  const int n0 = blockIdx.x * 128;

  const f16* gA  = Ah + (size_t)m0 * K;
  const f16* gW  = Wh + (size_t)n0 * K;
  const f16* gAl = (NSPLIT == 3) ? Al + (size_t)m0 * K : nullptr;
  const f16* gWl = (NSPLIT == 3) ? Wl + (size_t)n0 * K : nullptr;

  const int fbase = (l & 15) * 32 + (((l >> 4) ^ (l & 3)) * 8);
  const int fA = wm * 2048 + fbase;
  const int fW = wn * 2048 + fbase;

  const int s0   = w * 128 + l;
  const int dl0  = (w * 128) * 8;
  const int dl1  = (w * 128 + 64) * 8;

  f32x4 acc[4][4] = {};

  auto stage = [&](int k0, int bsel) {
    {
      const int s = s0;
      const int srow = s >> 2;
      const int koff = k0 + (((s & 3) ^ (srow & 3)) * 8);
      const size_t go = (size_t)srow * K + koff;
      gl16(gA + go, &smem[bsel][dl0]);
      gl16(gW + go, &smem[bsel][4096 + dl0]);
      if constexpr (NSPLIT == 3) {
        gl16(gAl + go, &smem[bsel][8192 + dl0]);
        gl16(gWl + go, &smem[bsel][12288 + dl0]);
      }
    }
    {
      const int s = s0 + 64;
      const int srow = s >> 2;
      const int koff = k0 + (((s & 3) ^ (srow & 3)) * 8);
      const size_t go = (size_t)srow * K + koff;
      gl16(gA + go, &smem[bsel][dl1]);
      gl16(gW + go, &smem[bsel][4096 + dl1]);
      if constexpr (NSPLIT == 3) {
        gl16(gAl + go, &smem[bsel][8192 + dl1]);
        gl16(gWl + go, &smem[bsel][12288 + dl1]);
      }
    }
  };

  stage(0, 0);
  __syncthreads();
  int buf = 0;

  for (int k0 = 0; k0 < K; k0 += 32) {
    if (k0 + 32 < K) stage(k0 + 32, buf ^ 1);   // async; in flight under MFMAs

    const f16* Ls = smem[buf];
    f16x8 ah[4], wh[4], al[4], wl[4];
#pragma unroll
    for (int i = 0; i < 4; ++i) ah[i] = *(const f16x8*)&Ls[fA + i * 512];
#pragma unroll
    for (int j = 0; j < 4; ++j) wh[j] = *(const f16x8*)&Ls[4096 + fW + j * 512];
    if constexpr (NSPLIT == 3) {
#pragma unroll
      for (int i = 0; i < 4; ++i) al[i] = *(const f16x8*)&Ls[8192 + fA + i * 512];
#pragma unroll
      for (int j = 0; j < 4; ++j) wl[j] = *(const f16x8*)&Ls[12288 + fW + j * 512];
    }

#pragma unroll
    for (int i = 0; i < 4; ++i)
#pragma unroll
      for (int j = 0; j < 4; ++j)
        acc[i][j] = __builtin_amdgcn_mfma_f32_16x16x32_f16(ah[i], wh[j], acc[i][j], 0, 0, 0);
    if constexpr (NSPLIT == 3) {
#pragma unroll
      for (int i = 0; i < 4; ++i)
#pragma unroll
        for (int j = 0; j < 4; ++j)
          acc[i][j] = __builtin_amdgcn_mfma_f32_16x16x32_f16(ah[i], wl[j], acc[i][j], 0, 0, 0);
#pragma unroll
      for (int i = 0; i < 4; ++i)
#pragma unroll
        for (int j = 0; j < 4; ++j)
          acc[i][j] = __builtin_amdgcn_mfma_f32_16x16x32_f16(al[i], wh[j], acc[i][j], 0, 0, 0);
    }
    __syncthreads();
    buf ^= 1;
  }

  const int rr = (l >> 4) * 4;
  const int cc = l & 15;
#pragma unroll
  for (int j = 0; j < 4; ++j) {
    const int n = n0 + wn * 64 + j * 16 + cc;
    const float bv = bias[n];
#pragma unroll
    for (int i = 0; i < 4; ++i) {
      const int m = m0 + wm * 64 + i * 16 + rr;
#pragma unroll
      for (int r = 0; r < 4; ++r) {
        const float val = acc[i][j][r] * inv + bv;
        if constexpr (OUT == 0) {
          C[(size_t)(m + r) * N + n] = val;
        } else {
          const float sv = val * oscale;
          const f16 hh = (f16)sv;
          const f16 ll = (f16)(sv - (float)hh);
          Ch[(size_t)(m + r) * N + n] = hh;
          Cl[(size_t)(m + r) * N + n] = ll;
        }
      }
    }
  }
}

// ---------------------------------------------------------------------------
// Canonical split-3 QK^T accumulation for one 32x32 tile. Same op order in
// main loop and slow-path recompute => bit-identical results.
// ---------------------------------------------------------------------------
__device__ __forceinline__ f32x16 qk_accum(const f16x8 ah[4], const f16x8 al[4],
                                           const f16x8 qh_[4], const f16x8 ql_[4]) {
  f32x16 ca = (f32x16){};
  f32x16 cb = (f32x16){};
  ca = MFMA32(ah[0], qh_[0], ca);  cb = MFMA32(ah[1], qh_[1], cb);
  ca = MFMA32(ah[2], qh_[2], ca);  cb = MFMA32(ah[3], qh_[3], cb);
  ca = MFMA32(al[0], qh_[0], ca);  cb = MFMA32(al[1], qh_[1], cb);
  ca = MFMA32(al[2], qh_[2], ca);  cb = MFMA32(al[3], qh_[3], cb);
  ca = MFMA32(ah[0], ql_[0], ca);  cb = MFMA32(ah[1], ql_[1], cb);
  ca = MFMA32(ah[2], ql_[2], ca);  cb = MFMA32(ah[3], ql_[3], cb);
  return ca + cb;
}

__device__ __forceinline__ f32x16 qk_tile_global(const f16* __restrict__ kgh,
                                                 const f16* __restrict__ kgl,
                                                 int tt, int q5, int hi5,
                                                 const f16x8 qh_[4], const f16x8 ql_[4]) {
  const f16* kh = kgh + (size_t)(tt * 32 + q5) * DE + hi5 * 8;
  const f16* kl = kgl + (size_t)(tt * 32 + q5) * DE + hi5 * 8;
  f16x8 ah[4], al[4];
#pragma unroll
  for (int s = 0; s < 4; ++s) {
    ah[s] = *(const f16x8*)(kh + s * 16);
    al[s] = *(const f16x8*)(kl + s * 16);
  }
  return qk_accum(ah, al, qh_, ql_);
}

// ---------------------------------------------------------------------------
// Fused sparse attention v13 — v11 structure; occupancy 4 blocks/CU,
// max3-fused tile max, paired Z/H accumulators. Selection semantics
// identical (max tree exact; Z/H order-change only shifts E at 1e-7
// against a ~190 margin on tk).
// ---------------------------------------------------------------------------
__global__ __launch_bounds__(256, 4)
void attn_v13(const f16* __restrict__ qhb, const f16* __restrict__ qlb,
              const f16* __restrict__ khb, const f16* __restrict__ klb,
              const float* __restrict__ vb, f16* __restrict__ ob) {
  __shared__ f16 Ks[2][2][4096];     // [dbuf][hi/lo][64kv x 64d swizzled] 32KB
  __shared__ float4 stat[4][32];     // per wave/row: {wt|-1, pa, pb, cnt}
  __shared__ int   sidx[4][48];      // slow-path gather lists (per wave)
  __shared__ float sp[4][48];
  __shared__ int   scnt[4][2];

  const int phys = blockIdx.x;
  const int bid = (phys & 7) * 128 + (phys >> 3);   // 1024 blocks, bijective
  const int b  = bid >> 7;
  const int h  = (bid >> 4) & 7;
  const int qt = bid & 15;
  const int tid = threadIdx.x;
  const int w  = tid >> 6;
  const int l  = tid & 63;
  const int q5 = l & 31;
  const int hi5 = l >> 5;

  const float C2 = 1.44269504f / 4096.0f;

  const int qrow = qt * 128 + w * 32 + q5;
  const f16* qpb = qhb + (size_t)(b * SQB + qrow) * DE + h * DH + hi5 * 8;
  const f16* qpl = qlb + (size_t)(b * SQB + qrow) * DE + h * DH + hi5 * 8;
  f16x8 qh_[4], ql_[4];
#pragma unroll
  for (int s = 0; s < 4; ++s) {
    qh_[s] = *(const f16x8*)(qpb + s * 16);
    ql_[s] = *(const f16x8*)(qpl + s * 16);
  }

  const f16* kgh = khb + (size_t)(b * SKVB) * DE + h * DH;
  const f16* kgl = klb + (size_t)(b * SKVB) * DE + h * DH;

  const int skv0 = tid >> 3;
  const int sch  = tid & 7;
  const int d_off0 = skv0 * 64 + ((sch ^ (skv0 & 7)) * 8);
  const int d_off1 = (32 + skv0) * 64 + ((sch ^ (skv0 & 7)) * 8);

  {
    const f16* shp = kgh + (size_t)skv0 * DE + sch * 8;
    const f16* slp = kgl + (size_t)skv0 * DE + sch * 8;
    uint4 a0 = *(const uint4*)(shp);
    uint4 a1 = *(const uint4*)(shp + 32 * DE);
    uint4 b0 = *(const uint4*)(slp);
    uint4 b1 = *(const uint4*)(slp + 32 * DE);
    *(uint4*)&Ks[0][0][d_off0] = a0;
    *(uint4*)&Ks[0][0][d_off1] = a1;
    *(uint4*)&Ks[0][1][d_off0] = b0;
    *(uint4*)&Ks[0][1][d_off1] = b1;
  }
  __syncthreads();

  float m = -INFINITY, Z0 = 0.f, Z1 = 0.f, H0 = 0.f, H1 = 0.f;
  int mt = 0;
  bool tie = false;
  f32x16 best = (f32x16){};

  for (int t = 0; t < 16; ++t) {
    const int cur = t & 1;
    const int nxt = cur ^ 1;
    uint4 La0, La1, Lb0, Lb1;
    const bool more = (t + 1 < 16);
    if (more) {
      const f16* shp = kgh + (size_t)((t + 1) * 64 + skv0) * DE + sch * 8;
      const f16* slp = kgl + (size_t)((t + 1) * 64 + skv0) * DE + sch * 8;
      La0 = *(const uint4*)(shp);
      La1 = *(const uint4*)(shp + 32 * DE);
      Lb0 = *(const uint4*)(slp);
      Lb1 = *(const uint4*)(slp + 32 * DE);
    }
#pragma unroll
    for (int u = 0; u < 2; ++u) {
      const int kvl = u * 32 + q5;
      const int rowoff = kvl * 64;
      f16x8 ah[4], al[4];
#pragma unroll
      for (int s = 0; s < 4; ++s) {
        const int idx = rowoff + (((s * 2 + hi5) ^ (q5 & 7)) * 8);
        ah[s] = *(const f16x8*)&Ks[cur][0][idx];
        al[s] = *(const f16x8*)&Ks[cur][1][idx];
      }
      const f32x16 sv = qk_accum(ah, al, qh_, ql_);
      // tile max via max3 fusion (exact: max is associative/commutative)
      const float g0 = fmaxf(fmaxf(sv[0], sv[1]), sv[2]);
      const float g1 = fmaxf(fmaxf(sv[3], sv[4]), sv[5]);
      const float g2 = fmaxf(fmaxf(sv[6], sv[7]), sv[8]);
      const float g3 = fmaxf(fmaxf(sv[9], sv[10]), sv[11]);
      const float g4 = fmaxf(fmaxf(sv[12], sv[13]), sv[14]);
      const float ga = fmaxf(fmaxf(g0, g1), g2);
      const float gb = fmaxf(fmaxf(g3, g4), sv[15]);
      const float tmax = fmaxf(ga, gb);
      // Z/H paired accumulation
#pragma unroll
      for (int r = 0; r < 16; r += 2) {
        const float s0 = sv[r];
        const float s1 = sv[r + 1];
        const float e0 = __builtin_amdgcn_exp2f(s0 * C2);
        const float e1 = __builtin_amdgcn_exp2f(s1 * C2);
        Z0 += e0;
        Z1 += e1;
        H0 = fmaf(e0, s0, H0);
        H1 = fmaf(e1, s1, H1);
      }
      const bool upd = (tmax > m);
      tie = upd ? false : (tie || (tmax == m));
      if (upd) { m = tmax; mt = t * 2 + u; }
#pragma unroll
      for (int r = 0; r < 16; ++r) best[r] = upd ? sv[r] : best[r];
    }
    if (more) {
      *(uint4*)&Ks[nxt][0][d_off0] = La0;
      *(uint4*)&Ks[nxt][0][d_off1] = La1;
      *(uint4*)&Ks[nxt][1][d_off0] = Lb0;
      *(uint4*)&Ks[nxt][1][d_off1] = Lb1;
    }
    __syncthreads();
  }

  float Z = Z0 + Z1;
  float H = H0 + H1;
  const float mo = __shfl_xor(m, 32);
  const int tieo = __shfl_xor(tie ? 1 : 0, 32);
  Z += __shfl_xor(Z, 32);
  H += __shfl_xor(H, 32);
  const float mc = fmaxf(m, mo);
  const bool tiec = (m > mo) ? tie : ((mo > m) ? (tieo != 0) : (tie || tieo != 0));

  int c = 0, p1 = -1, p2 = -1;
#pragma unroll
  for (int r = 0; r < 16; ++r) {
    if (best[r] == mc) {
      const int pos = mt * 32 + (r & 3) + 8 * (r >> 2) + 4 * hi5;
      p2 = (c == 1) ? pos : p2;
      p1 = (c == 0) ? pos : p1;
      ++c;
    }
  }
  const int co  = __shfl_xor(c, 32);
  const int p1o = __shfl_xor(p1, 32);
  const int p2o = __shfl_xor(p2, 32);
  const int ct = c + co;
  const int pa = (c > 0) ? p1 : p1o;
  const int pb = (c >= 2) ? p2 : ((c == 1) ? ((co > 0) ? p1o : -1)
                                           : ((co >= 2) ? p2o : -1));

  const float E = __logf(Z) - (H * (1.0f / 4096.0f)) / Z;
  int tk = (int)(32.0f * (1.0f - E));
  tk = tk < 1 ? 1 : (tk > 32 ? 32 : tk);
  const bool slowRow = (tk > 1) || tiec || (ct > 2);
  const float zeps = 1e-8f * Z * __builtin_amdgcn_exp2f(-mc * C2);
  const float wt = 1.0f / ((float)ct + zeps);

  if (hi5 == 0)
    stat[w][q5] = make_float4(slowRow ? -1.0f : wt,
                              __int_as_float(pa),
                              __int_as_float(ct == 2 ? pb : -1),
                              (float)ct);

  {
    const size_t obase = (size_t)(b * SQB + qt * 128 + w * 32) * DE + h * DH + l;
    const float* vB = vb + (size_t)(b * SKVB) * DE + h * DH + l;
    for (int r = 0; r < 32; ++r) {
      const float4 st = stat[w][r];
      if (st.x >= 0.f) {
        const int ppa = __float_as_int(st.y);
        const int ppb = __float_as_int(st.z);
        float acc = vB[(size_t)ppa * DE];
        if (ppb >= 0) acc += vB[(size_t)ppb * DE];
        ob[obase + (size_t)r * DE] = (f16)(acc * st.x);
      }
    }
  }

  {
    unsigned long long sb = __ballot(slowRow && hi5 == 0);
    while (sb != 0ull) {
      const int rr = (int)__builtin_ctzll(sb);
      sb &= sb - 1;
      const float mr = __shfl(mc, rr);
      const int tkr  = __shfl(tk, rr);
      const float Zr = __shfl(Z, rr);
      float thr = mr;
      float rem = (float)tkr;
      float cand = mr;
      int guard = 0;
      bool done = false;
      while (!done && guard < 40) {
        ++guard;
        float cf = 0.f, nmx = -INFINITY;
        for (int tt = 0; tt < 32; ++tt) {
          const f32x16 sv = qk_tile_global(kgh, kgl, tt, q5, hi5, qh_, ql_);
          if (q5 == rr) {
#pragma unroll
            for (int r = 0; r < 16; ++r) {
              cf += (sv[r] == cand) ? 1.f : 0.f;
              nmx = (sv[r] < cand) ? fmaxf(nmx, sv[r]) : nmx;
            }
          }
        }
        cf += __shfl_xor(cf, 32);
        nmx = fmaxf(nmx, __shfl_xor(nmx, 32));
        const float cfr = __shfl(cf, rr);
        const float nmr = __shfl(nmx, rr);
        if (cfr >= rem) { thr = cand; done = true; }
        else { rem -= cfr; cand = nmr; }
      }
      int myc = 0;
      for (int tt = 0; tt < 32; ++tt) {
        const f32x16 sv = qk_tile_global(kgh, kgl, tt, q5, hi5, qh_, ql_);
        if (q5 == rr) {
#pragma unroll
          for (int r = 0; r < 16; ++r) {
            if (sv[r] >= thr && myc < 24) {
              sidx[w][hi5 * 24 + myc] = tt * 32 + (r & 3) + 8 * (r >> 2) + 4 * hi5;
              sp[w][hi5 * 24 + myc] = __builtin_amdgcn_exp2f((sv[r] - mr) * C2);
              ++myc;
            }
          }
        }
      }
      if (q5 == rr) scnt[w][hi5] = myc;
      int c0 = scnt[w][0]; c0 = c0 > 24 ? 24 : c0;
      int c1 = scnt[w][1]; c1 = c1 > 24 ? 24 : c1;
      float acc = 0.f, ps = 0.f;
      const float* vB = vb + (size_t)(b * SKVB) * DE + h * DH + l;
      for (int e = 0; e < c0; ++e) {
        const int kv = sidx[w][e]; const float p = sp[w][e];
        ps += p; acc = fmaf(p, vB[(size_t)kv * DE], acc);
      }
      for (int e = 0; e < c1; ++e) {
        const int kv = sidx[w][24 + e]; const float p = sp[w][24 + e];
        ps += p; acc = fmaf(p, vB[(size_t)kv * DE], acc);
      }
      const float zepsr = 1e-8f * Zr * __builtin_amdgcn_exp2f(-mr * C2);
      const float o = acc / (ps + zepsr);
      ob[(size_t)(b * SQB + qt * 128 + w * 32 + rr) * DE + h * DH + l] = (f16)o;
    }
  }
}

// ---------------------------------------------------------------------------
extern "C" void kernel_launch(void* const* d_in, const int* in_sizes, int n_in,
                              void* d_out, int out_size, void* d_ws, size_t ws_size,
                              hipStream_t stream) {
  const float* x  = (const float*)d_in[0];
  const float* y  = (const float*)d_in[1];
  const float* wq = (const float*)d_in[2];
  const float* bq = (const float*)d_in[3];
  const float* wk = (const float*)d_in[4];
  const float* bk = (const float*)d_in[5];
  const float* wv = (const float*)d_in[6];
  const float* bv = (const float*)d_in[7];
  const float* wo = (const float*)d_in[8];
  const float* bo = (const float*)d_in[9];
  float* out = (float*)d_out;

  char* ws = (char*)d_ws;
  const size_t MiB = 1048576;

  f16* xh  = (f16*)(ws);                       // 16 MiB
  f16* xl  = (f16*)(ws + 16 * MiB);            // 16
  f16* yh  = (f16*)(ws + 32 * MiB);            // 12
  f16* yl  = (f16*)(ws + 44 * MiB);            // 12
  f16* qh  = (f16*)(ws + 56 * MiB);            // 16
  f16* ql  = (f16*)(ws + 72 * MiB);            // 16
  f16* kh  = (f16*)(ws + 88 * MiB);            // 8
  f16* kl  = (f16*)(ws + 96 * MiB);            // 8
  float* v = (float*)(ws + 104 * MiB);         // 16 (f32)
  f16* ao  = (f16*)(ws + 120 * MiB);           // 16
  f16* wqh = (f16*)(ws + 136 * MiB);
  f16* wql = (f16*)(ws + 136 * MiB + 524288);
  f16* wkh = (f16*)(ws + 137 * MiB);
  f16* wkl = (f16*)(ws + 137 * MiB + 786432);
  f16* wvh = (f16*)(ws + 138 * MiB + 524288);
  f16* wvl = (f16*)(ws + 139 * MiB + 262144);
  f16* woh = (f16*)(ws + 140 * MiB);
  f16* wol = (f16*)(ws + 140 * MiB + 524288);

  dim3 blk(256);
  const float WS = 2048.0f, IWS = 1.0f / 2048.0f;

  split2<<<dim3(14336), blk, 0, stream>>>(x, xh, xl, 2097152,
                                          y, yh, yl, 1572864);
  split4<<<dim3(1280), blk, 0, stream>>>(wq, wqh, wql, 65536, WS,
                                         wk, wkh, wkl, 98304, WS,
                                         wv, wvh, wvl, 98304, 1.0f,
                                         wo, woh, wol, 65536, 1.0f);

  // Q-proj -> split pair scaled x8  (q_true * 0.125 * 64)
  gemm_f16<3, 1><<<dim3(4, 128), blk, 0, stream>>>(xh, xl, wqh, wql, bq,
      nullptr, qh, ql, 16384, 512, 512, IWS, 8.0f);
  // K-proj -> split pair scaled x64
  gemm_f16<3, 1><<<dim3(4, 64), blk, 0, stream>>>(yh, yl, wkh, wkl, bk,
      nullptr, kh, kl, 8192, 512, 768, IWS, 64.0f);
  // V-proj -> f32
  gemm_f16<1, 0><<<dim3(4, 64), blk, 0, stream>>>(yh, nullptr, wvh, nullptr, bv,
      v, nullptr, nullptr, 8192, 512, 768, 1.0f, 1.0f);

  attn_v13<<<dim3(1024), blk, 0, stream>>>(qh, ql, kh, kl, v, ao);

  // O-proj
  gemm_f16<1, 0><<<dim3(4, 128), blk, 0, stream>>>(ao, nullptr, woh, nullptr, bo,
      out, nullptr, nullptr, 16384, 512, 512, 1.0f, 1.0f);
}

// Round 15
// 214.045 us; speedup vs baseline: 1.2605x; 1.2605x over previous
//
#include <hip/hip_runtime.h>
#include <cstdint>
#include <cmath>

#define DH 64
#define SQB 2048
#define SKVB 1024
#define DE 512

typedef _Float16 f16;
typedef _Float16 f16x8 __attribute__((ext_vector_type(8)));
typedef float f32x4 __attribute__((ext_vector_type(4)));
typedef float f32x16 __attribute__((ext_vector_type(16)));
typedef unsigned int u32;

#define MFMA32(A, B, C) __builtin_amdgcn_mfma_f32_32x32x16_f16(A, B, C, 0, 0, 0)

// ---------------------------------------------------------------------------
// async global->LDS 16B (wave-uniform LDS base + lane*16; global addr per-lane)
// ---------------------------------------------------------------------------
__device__ __forceinline__ void gl16(const f16* g, f16* l) {
  __builtin_amdgcn_global_load_lds(
      (const __attribute__((address_space(1))) u32*)g,
      (__attribute__((address_space(3))) u32*)l, 16, 0, 0);
}

// ---------------------------------------------------------------------------
// split helpers
// ---------------------------------------------------------------------------
__device__ __forceinline__ void do_split(const float* __restrict__ in,
                                         f16* __restrict__ hi, f16* __restrict__ lo,
                                         int i, float scale) {
  float4 v = ((const float4*)in)[i];
  v.x *= scale; v.y *= scale; v.z *= scale; v.w *= scale;
  f16 h0 = (f16)v.x, h1 = (f16)v.y, h2 = (f16)v.z, h3 = (f16)v.w;
  f16 l0 = (f16)(v.x - (float)h0), l1 = (f16)(v.y - (float)h1);
  f16 l2 = (f16)(v.z - (float)h2), l3 = (f16)(v.w - (float)h3);
  f16 hb[4] = {h0, h1, h2, h3};
  f16 lb[4] = {l0, l1, l2, l3};
  ((uint2*)hi)[i] = *(const uint2*)hb;
  ((uint2*)lo)[i] = *(const uint2*)lb;
}

// x + y in one launch (scale 1.0 both)
__global__ __launch_bounds__(256)
void split2(const float* __restrict__ a, f16* __restrict__ ah, f16* __restrict__ al, int na,
            const float* __restrict__ b, f16* __restrict__ bh, f16* __restrict__ bl, int nb) {
  const int i = blockIdx.x * 256 + threadIdx.x;
  if (i < na) do_split(a, ah, al, i, 1.0f);
  else if (i < na + nb) do_split(b, bh, bl, i - na, 1.0f);
}

// all four weights in one launch
__global__ __launch_bounds__(256)
void split4(const float* __restrict__ a, f16* __restrict__ ah, f16* __restrict__ al, int na, float sa,
            const float* __restrict__ b, f16* __restrict__ bh, f16* __restrict__ bl, int nb, float sb,
            const float* __restrict__ c, f16* __restrict__ ch, f16* __restrict__ cl, int nc, float sc,
            const float* __restrict__ d, f16* __restrict__ dh, f16* __restrict__ dl, int nd, float sd) {
  int i = blockIdx.x * 256 + threadIdx.x;
  if (i < na) { do_split(a, ah, al, i, sa); return; }
  i -= na;
  if (i < nb) { do_split(b, bh, bl, i, sb); return; }
  i -= nb;
  if (i < nc) { do_split(c, ch, cl, i, sc); return; }
  i -= nc;
  if (i < nd) do_split(d, dh, dl, i, sd);
}

// ---------------------------------------------------------------------------
// MFMA f16 GEMM — R4-validated math, global_load_lds(16) staging with
// pre-swizzled global source. Double-buffered, one barrier per K-step.
// NSPLIT=1 kernels (32KB LDS) run at 4 blocks/CU; NSPLIT=3 (64KB) at 2.
// OUT=0: C fp32. OUT=1: split-f16 pair of (C * oscale).
// ---------------------------------------------------------------------------
template <int NSPLIT, int OUT>
__global__ __launch_bounds__(256, NSPLIT == 3 ? 2 : 4)
void gemm_f16(const f16* __restrict__ Ah, const f16* __restrict__ Al,
              const f16* __restrict__ Wh, const f16* __restrict__ Wl,
              const float* __restrict__ bias, float* __restrict__ C,
              f16* __restrict__ Ch, f16* __restrict__ Cl,
              int M, int N, int K, float inv, float oscale) {
  constexpr int NPART = (NSPLIT == 3) ? 4 : 2;
  __shared__ f16 smem[2][NPART * 4096];   // parts: As, Ws, (Als, Wls)

  const int tid = threadIdx.x;
  const int w = tid >> 6;
  const int l = tid & 63;
  const int wm = w >> 1, wn = w & 1;
  const int m0 = blockIdx.y * 128;
  const int n0 = blockIdx.x * 128;

  const f16* gA  = Ah + (size_t)m0 * K;
  const f16* gW  = Wh + (size_t)n0 * K;
  const f16* gAl = (NSPLIT == 3) ? Al + (size_t)m0 * K : nullptr;
  const f16* gWl = (NSPLIT == 3) ? Wl + (size_t)n0 * K : nullptr;

  const int fbase = (l & 15) * 32 + (((l >> 4) ^ (l & 3)) * 8);
  const int fA = wm * 2048 + fbase;
  const int fW = wn * 2048 + fbase;

  const int s0   = w * 128 + l;
  const int dl0  = (w * 128) * 8;
  const int dl1  = (w * 128 + 64) * 8;

  f32x4 acc[4][4] = {};

  auto stage = [&](int k0, int bsel) {
    {
      const int s = s0;
      const int srow = s >> 2;
      const int koff = k0 + (((s & 3) ^ (srow & 3)) * 8);
      const size_t go = (size_t)srow * K + koff;
      gl16(gA + go, &smem[bsel][dl0]);
      gl16(gW + go, &smem[bsel][4096 + dl0]);
      if constexpr (NSPLIT == 3) {
        gl16(gAl + go, &smem[bsel][8192 + dl0]);
        gl16(gWl + go, &smem[bsel][12288 + dl0]);
      }
    }
    {
      const int s = s0 + 64;
      const int srow = s >> 2;
      const int koff = k0 + (((s & 3) ^ (srow & 3)) * 8);
      const size_t go = (size_t)srow * K + koff;
      gl16(gA + go, &smem[bsel][dl1]);
      gl16(gW + go, &smem[bsel][4096 + dl1]);
      if constexpr (NSPLIT == 3) {
        gl16(gAl + go, &smem[bsel][8192 + dl1]);
        gl16(gWl + go, &smem[bsel][12288 + dl1]);
      }
    }
  };

  stage(0, 0);
  __syncthreads();
  int buf = 0;

  for (int k0 = 0; k0 < K; k0 += 32) {
    if (k0 + 32 < K) stage(k0 + 32, buf ^ 1);   // async; in flight under MFMAs

    const f16* Ls = smem[buf];
    f16x8 ah[4], wh[4], al[4], wl[4];
#pragma unroll
    for (int i = 0; i < 4; ++i) ah[i] = *(const f16x8*)&Ls[fA + i * 512];
#pragma unroll
    for (int j = 0; j < 4; ++j) wh[j] = *(const f16x8*)&Ls[4096 + fW + j * 512];
    if constexpr (NSPLIT == 3) {
#pragma unroll
      for (int i = 0; i < 4; ++i) al[i] = *(const f16x8*)&Ls[8192 + fA + i * 512];
#pragma unroll
      for (int j = 0; j < 4; ++j) wl[j] = *(const f16x8*)&Ls[12288 + fW + j * 512];
    }

#pragma unroll
    for (int i = 0; i < 4; ++i)
#pragma unroll
      for (int j = 0; j < 4; ++j)
        acc[i][j] = __builtin_amdgcn_mfma_f32_16x16x32_f16(ah[i], wh[j], acc[i][j], 0, 0, 0);
    if constexpr (NSPLIT == 3) {
#pragma unroll
      for (int i = 0; i < 4; ++i)
#pragma unroll
        for (int j = 0; j < 4; ++j)
          acc[i][j] = __builtin_amdgcn_mfma_f32_16x16x32_f16(ah[i], wl[j], acc[i][j], 0, 0, 0);
#pragma unroll
      for (int i = 0; i < 4; ++i)
#pragma unroll
        for (int j = 0; j < 4; ++j)
          acc[i][j] = __builtin_amdgcn_mfma_f32_16x16x32_f16(al[i], wh[j], acc[i][j], 0, 0, 0);
    }
    __syncthreads();
    buf ^= 1;
  }

  const int rr = (l >> 4) * 4;
  const int cc = l & 15;
#pragma unroll
  for (int j = 0; j < 4; ++j) {
    const int n = n0 + wn * 64 + j * 16 + cc;
    const float bv = bias[n];
#pragma unroll
    for (int i = 0; i < 4; ++i) {
      const int m = m0 + wm * 64 + i * 16 + rr;
#pragma unroll
      for (int r = 0; r < 4; ++r) {
        const float val = acc[i][j][r] * inv + bv;
        if constexpr (OUT == 0) {
          C[(size_t)(m + r) * N + n] = val;
        } else {
          const float sv = val * oscale;
          const f16 hh = (f16)sv;
          const f16 ll = (f16)(sv - (float)hh);
          Ch[(size_t)(m + r) * N + n] = hh;
          Cl[(size_t)(m + r) * N + n] = ll;
        }
      }
    }
  }
}

// ---------------------------------------------------------------------------
// Canonical split-3 QK^T accumulation for one 32x32 tile. Same op order in
// main loop and slow-path recompute => bit-identical results.
// ---------------------------------------------------------------------------
__device__ __forceinline__ f32x16 qk_accum(const f16x8 ah[4], const f16x8 al[4],
                                           const f16x8 qh_[4], const f16x8 ql_[4]) {
  f32x16 ca = (f32x16){};
  f32x16 cb = (f32x16){};
  ca = MFMA32(ah[0], qh_[0], ca);  cb = MFMA32(ah[1], qh_[1], cb);
  ca = MFMA32(ah[2], qh_[2], ca);  cb = MFMA32(ah[3], qh_[3], cb);
  ca = MFMA32(al[0], qh_[0], ca);  cb = MFMA32(al[1], qh_[1], cb);
  ca = MFMA32(al[2], qh_[2], ca);  cb = MFMA32(al[3], qh_[3], cb);
  ca = MFMA32(ah[0], ql_[0], ca);  cb = MFMA32(ah[1], ql_[1], cb);
  ca = MFMA32(ah[2], ql_[2], ca);  cb = MFMA32(ah[3], ql_[3], cb);
  return ca + cb;
}

__device__ __forceinline__ f32x16 qk_tile_global(const f16* __restrict__ kgh,
                                                 const f16* __restrict__ kgl,
                                                 int tt, int q5, int hi5,
                                                 const f16x8 qh_[4], const f16x8 ql_[4]) {
  const f16* kh = kgh + (size_t)(tt * 32 + q5) * DE + hi5 * 8;
  const f16* kl = kgl + (size_t)(tt * 32 + q5) * DE + hi5 * 8;
  f16x8 ah[4], al[4];
#pragma unroll
  for (int s = 0; s < 4; ++s) {
    ah[s] = *(const f16x8*)(kh + s * 16);
    al[s] = *(const f16x8*)(kl + s * 16);
  }
  return qk_accum(ah, al, qh_, ql_);
}

// ---------------------------------------------------------------------------
// Fused sparse attention v14 — v11 structure at the PROVEN occupancy
// (3 blocks/CU; v13's 4-cap forced 64 VGPR -> scratch spill, reverted).
// Keeps max3 tile-max + paired Z/H accumulators (selection semantics
// identical; exact max tree; Z/H order shift ~1e-7 vs tk margin ~190).
// ---------------------------------------------------------------------------
__global__ __launch_bounds__(256, 3)
void attn_v14(const f16* __restrict__ qhb, const f16* __restrict__ qlb,
              const f16* __restrict__ khb, const f16* __restrict__ klb,
              const float* __restrict__ vb, f16* __restrict__ ob) {
  __shared__ f16 Ks[2][2][4096];     // [dbuf][hi/lo][64kv x 64d swizzled] 32KB
  __shared__ float4 stat[4][32];     // per wave/row: {wt|-1, pa, pb, cnt}
  __shared__ int   sidx[4][48];      // slow-path gather lists (per wave)
  __shared__ float sp[4][48];
  __shared__ int   scnt[4][2];

  const int phys = blockIdx.x;
  const int bid = (phys & 7) * 128 + (phys >> 3);   // 1024 blocks, bijective
  const int b  = bid >> 7;
  const int h  = (bid >> 4) & 7;
  const int qt = bid & 15;
  const int tid = threadIdx.x;
  const int w  = tid >> 6;
  const int l  = tid & 63;
  const int q5 = l & 31;
  const int hi5 = l >> 5;

  const float C2 = 1.44269504f / 4096.0f;

  const int qrow = qt * 128 + w * 32 + q5;
  const f16* qpb = qhb + (size_t)(b * SQB + qrow) * DE + h * DH + hi5 * 8;
  const f16* qpl = qlb + (size_t)(b * SQB + qrow) * DE + h * DH + hi5 * 8;
  f16x8 qh_[4], ql_[4];
#pragma unroll
  for (int s = 0; s < 4; ++s) {
    qh_[s] = *(const f16x8*)(qpb + s * 16);
    ql_[s] = *(const f16x8*)(qpl + s * 16);
  }

  const f16* kgh = khb + (size_t)(b * SKVB) * DE + h * DH;
  const f16* kgl = klb + (size_t)(b * SKVB) * DE + h * DH;

  const int skv0 = tid >> 3;
  const int sch  = tid & 7;
  const int d_off0 = skv0 * 64 + ((sch ^ (skv0 & 7)) * 8);
  const int d_off1 = (32 + skv0) * 64 + ((sch ^ (skv0 & 7)) * 8);

  {
    const f16* shp = kgh + (size_t)skv0 * DE + sch * 8;
    const f16* slp = kgl + (size_t)skv0 * DE + sch * 8;
    uint4 a0 = *(const uint4*)(shp);
    uint4 a1 = *(const uint4*)(shp + 32 * DE);
    uint4 b0 = *(const uint4*)(slp);
    uint4 b1 = *(const uint4*)(slp + 32 * DE);
    *(uint4*)&Ks[0][0][d_off0] = a0;
    *(uint4*)&Ks[0][0][d_off1] = a1;
    *(uint4*)&Ks[0][1][d_off0] = b0;
    *(uint4*)&Ks[0][1][d_off1] = b1;
  }
  __syncthreads();

  float m = -INFINITY, Z0 = 0.f, Z1 = 0.f, H0 = 0.f, H1 = 0.f;
  int mt = 0;
  bool tie = false;
  f32x16 best = (f32x16){};

  for (int t = 0; t < 16; ++t) {
    const int cur = t & 1;
    const int nxt = cur ^ 1;
    uint4 La0, La1, Lb0, Lb1;
    const bool more = (t + 1 < 16);
    if (more) {
      const f16* shp = kgh + (size_t)((t + 1) * 64 + skv0) * DE + sch * 8;
      const f16* slp = kgl + (size_t)((t + 1) * 64 + skv0) * DE + sch * 8;
      La0 = *(const uint4*)(shp);
      La1 = *(const uint4*)(shp + 32 * DE);
      Lb0 = *(const uint4*)(slp);
      Lb1 = *(const uint4*)(slp + 32 * DE);
    }
#pragma unroll
    for (int u = 0; u < 2; ++u) {
      const int kvl = u * 32 + q5;
      const int rowoff = kvl * 64;
      f16x8 ah[4], al[4];
#pragma unroll
      for (int s = 0; s < 4; ++s) {
        const int idx = rowoff + (((s * 2 + hi5) ^ (q5 & 7)) * 8);
        ah[s] = *(const f16x8*)&Ks[cur][0][idx];
        al[s] = *(const f16x8*)&Ks[cur][1][idx];
      }
      const f32x16 sv = qk_accum(ah, al, qh_, ql_);
      // tile max via max3 fusion (exact: max is associative/commutative)
      const float g0 = fmaxf(fmaxf(sv[0], sv[1]), sv[2]);
      const float g1 = fmaxf(fmaxf(sv[3], sv[4]), sv[5]);
      const float g2 = fmaxf(fmaxf(sv[6], sv[7]), sv[8]);
      const float g3 = fmaxf(fmaxf(sv[9], sv[10]), sv[11]);
      const float g4 = fmaxf(fmaxf(sv[12], sv[13]), sv[14]);
      const float ga = fmaxf(fmaxf(g0, g1), g2);
      const float gb = fmaxf(fmaxf(g3, g4), sv[15]);
      const float tmax = fmaxf(ga, gb);
      // Z/H paired accumulation
#pragma unroll
      for (int r = 0; r < 16; r += 2) {
        const float s0 = sv[r];
        const float s1 = sv[r + 1];
        const float e0 = __builtin_amdgcn_exp2f(s0 * C2);
        const float e1 = __builtin_amdgcn_exp2f(s1 * C2);
        Z0 += e0;
        Z1 += e1;
        H0 = fmaf(e0, s0, H0);
        H1 = fmaf(e1, s1, H1);
      }
      const bool upd = (tmax > m);
      tie = upd ? false : (tie || (tmax == m));
      if (upd) { m = tmax; mt = t * 2 + u; }
#pragma unroll
      for (int r = 0; r < 16; ++r) best[r] = upd ? sv[r] : best[r];
    }
    if (more) {
      *(uint4*)&Ks[nxt][0][d_off0] = La0;
      *(uint4*)&Ks[nxt][0][d_off1] = La1;
      *(uint4*)&Ks[nxt][1][d_off0] = Lb0;
      *(uint4*)&Ks[nxt][1][d_off1] = Lb1;
    }
    __syncthreads();
  }

  float Z = Z0 + Z1;
  float H = H0 + H1;
  const float mo = __shfl_xor(m, 32);
  const int tieo = __shfl_xor(tie ? 1 : 0, 32);
  Z += __shfl_xor(Z, 32);
  H += __shfl_xor(H, 32);
  const float mc = fmaxf(m, mo);
  const bool tiec = (m > mo) ? tie : ((mo > m) ? (tieo != 0) : (tie || tieo != 0));

  int c = 0, p1 = -1, p2 = -1;
#pragma unroll
  for (int r = 0; r < 16; ++r) {
    if (best[r] == mc) {
      const int pos = mt * 32 + (r & 3) + 8 * (r >> 2) + 4 * hi5;
      p2 = (c == 1) ? pos : p2;
      p1 = (c == 0) ? pos : p1;
      ++c;
    }
  }
  const int co  = __shfl_xor(c, 32);
  const int p1o = __shfl_xor(p1, 32);
  const int p2o = __shfl_xor(p2, 32);
  const int ct = c + co;
  const int pa = (c > 0) ? p1 : p1o;
  const int pb = (c >= 2) ? p2 : ((c == 1) ? ((co > 0) ? p1o : -1)
                                           : ((co >= 2) ? p2o : -1));

  const float E = __logf(Z) - (H * (1.0f / 4096.0f)) / Z;
  int tk = (int)(32.0f * (1.0f - E));
  tk = tk < 1 ? 1 : (tk > 32 ? 32 : tk);
  const bool slowRow = (tk > 1) || tiec || (ct > 2);
  const float zeps = 1e-8f * Z * __builtin_amdgcn_exp2f(-mc * C2);
  const float wt = 1.0f / ((float)ct + zeps);

  if (hi5 == 0)
    stat[w][q5] = make_float4(slowRow ? -1.0f : wt,
                              __int_as_float(pa),
                              __int_as_float(ct == 2 ? pb : -1),
                              (float)ct);

  {
    const size_t obase = (size_t)(b * SQB + qt * 128 + w * 32) * DE + h * DH + l;
    const float* vB = vb + (size_t)(b * SKVB) * DE + h * DH + l;
    for (int r = 0; r < 32; ++r) {
      const float4 st = stat[w][r];
      if (st.x >= 0.f) {
        const int ppa = __float_as_int(st.y);
        const int ppb = __float_as_int(st.z);
        float acc = vB[(size_t)ppa * DE];
        if (ppb >= 0) acc += vB[(size_t)ppb * DE];
        ob[obase + (size_t)r * DE] = (f16)(acc * st.x);
      }
    }
  }

  {
    unsigned long long sb = __ballot(slowRow && hi5 == 0);
    while (sb != 0ull) {
      const int rr = (int)__builtin_ctzll(sb);
      sb &= sb - 1;
      const float mr = __shfl(mc, rr);
      const int tkr  = __shfl(tk, rr);
      const float Zr = __shfl(Z, rr);
      float thr = mr;
      float rem = (float)tkr;
      float cand = mr;
      int guard = 0;
      bool done = false;
      while (!done && guard < 40) {
        ++guard;
        float cf = 0.f, nmx = -INFINITY;
        for (int tt = 0; tt < 32; ++tt) {
          const f32x16 sv = qk_tile_global(kgh, kgl, tt, q5, hi5, qh_, ql_);
          if (q5 == rr) {
#pragma unroll
            for (int r = 0; r < 16; ++r) {
              cf += (sv[r] == cand) ? 1.f : 0.f;
              nmx = (sv[r] < cand) ? fmaxf(nmx, sv[r]) : nmx;
            }
          }
        }
        cf += __shfl_xor(cf, 32);
        nmx = fmaxf(nmx, __shfl_xor(nmx, 32));
        const float cfr = __shfl(cf, rr);
        const float nmr = __shfl(nmx, rr);
        if (cfr >= rem) { thr = cand; done = true; }
        else { rem -= cfr; cand = nmr; }
      }
      int myc = 0;
      for (int tt = 0; tt < 32; ++tt) {
        const f32x16 sv = qk_tile_global(kgh, kgl, tt, q5, hi5, qh_, ql_);
        if (q5 == rr) {
#pragma unroll
          for (int r = 0; r < 16; ++r) {
            if (sv[r] >= thr && myc < 24) {
              sidx[w][hi5 * 24 + myc] = tt * 32 + (r & 3) + 8 * (r >> 2) + 4 * hi5;
              sp[w][hi5 * 24 + myc] = __builtin_amdgcn_exp2f((sv[r] - mr) * C2);
              ++myc;
            }
          }
        }
      }
      if (q5 == rr) scnt[w][hi5] = myc;
      int c0 = scnt[w][0]; c0 = c0 > 24 ? 24 : c0;
      int c1 = scnt[w][1]; c1 = c1 > 24 ? 24 : c1;
      float acc = 0.f, ps = 0.f;
      const float* vB = vb + (size_t)(b * SKVB) * DE + h * DH + l;
      for (int e = 0; e < c0; ++e) {
        const int kv = sidx[w][e]; const float p = sp[w][e];
        ps += p; acc = fmaf(p, vB[(size_t)kv * DE], acc);
      }
      for (int e = 0; e < c1; ++e) {
        const int kv = sidx[w][24 + e]; const float p = sp[w][24 + e];
        ps += p; acc = fmaf(p, vB[(size_t)kv * DE], acc);
      }
      const float zepsr = 1e-8f * Zr * __builtin_amdgcn_exp2f(-mr * C2);
      const float o = acc / (ps + zepsr);
      ob[(size_t)(b * SQB + qt * 128 + w * 32 + rr) * DE + h * DH + l] = (f16)o;
    }
  }
}

// ---------------------------------------------------------------------------
extern "C" void kernel_launch(void* const* d_in, const int* in_sizes, int n_in,
                              void* d_out, int out_size, void* d_ws, size_t ws_size,
                              hipStream_t stream) {
  const float* x  = (const float*)d_in[0];
  const float* y  = (const float*)d_in[1];
  const float* wq = (const float*)d_in[2];
  const float* bq = (const float*)d_in[3];
  const float* wk = (const float*)d_in[4];
  const float* bk = (const float*)d_in[5];
  const float* wv = (const float*)d_in[6];
  const float* bv = (const float*)d_in[7];
  const float* wo = (const float*)d_in[8];
  const float* bo = (const float*)d_in[9];
  float* out = (float*)d_out;

  char* ws = (char*)d_ws;
  const size_t MiB = 1048576;

  f16* xh  = (f16*)(ws);                       // 16 MiB
  f16* xl  = (f16*)(ws + 16 * MiB);            // 16
  f16* yh  = (f16*)(ws + 32 * MiB);            // 12
  f16* yl  = (f16*)(ws + 44 * MiB);            // 12
  f16* qh  = (f16*)(ws + 56 * MiB);            // 16
  f16* ql  = (f16*)(ws + 72 * MiB);            // 16
  f16* kh  = (f16*)(ws + 88 * MiB);            // 8
  f16* kl  = (f16*)(ws + 96 * MiB);            // 8
  float* v = (float*)(ws + 104 * MiB);         // 16 (f32)
  f16* ao  = (f16*)(ws + 120 * MiB);           // 16
  f16* wqh = (f16*)(ws + 136 * MiB);
  f16* wql = (f16*)(ws + 136 * MiB + 524288);
  f16* wkh = (f16*)(ws + 137 * MiB);
  f16* wkl = (f16*)(ws + 137 * MiB + 786432);
  f16* wvh = (f16*)(ws + 138 * MiB + 524288);
  f16* wvl = (f16*)(ws + 139 * MiB + 262144);
  f16* woh = (f16*)(ws + 140 * MiB);
  f16* wol = (f16*)(ws + 140 * MiB + 524288);

  dim3 blk(256);
  const float WS = 2048.0f, IWS = 1.0f / 2048.0f;

  split2<<<dim3(14336), blk, 0, stream>>>(x, xh, xl, 2097152,
                                          y, yh, yl, 1572864);
  split4<<<dim3(1280), blk, 0, stream>>>(wq, wqh, wql, 65536, WS,
                                         wk, wkh, wkl, 98304, WS,
                                         wv, wvh, wvl, 98304, 1.0f,
                                         wo, woh, wol, 65536, 1.0f);

  // Q-proj -> split pair scaled x8  (q_true * 0.125 * 64)
  gemm_f16<3, 1><<<dim3(4, 128), blk, 0, stream>>>(xh, xl, wqh, wql, bq,
      nullptr, qh, ql, 16384, 512, 512, IWS, 8.0f);
  // K-proj -> split pair scaled x64
  gemm_f16<3, 1><<<dim3(4, 64), blk, 0, stream>>>(yh, yl, wkh, wkl, bk,
      nullptr, kh, kl, 8192, 512, 768, IWS, 64.0f);
  // V-proj -> f32
  gemm_f16<1, 0><<<dim3(4, 64), blk, 0, stream>>>(yh, nullptr, wvh, nullptr, bv,
      v, nullptr, nullptr, 8192, 512, 768, 1.0f, 1.0f);

  attn_v14<<<dim3(1024), blk, 0, stream>>>(qh, ql, kh, kl, v, ao);

  // O-proj
  gemm_f16<1, 0><<<dim3(4, 128), blk, 0, stream>>>(ao, nullptr, woh, nullptr, bo,
      out, nullptr, nullptr, 16384, 512, 512, 1.0f, 1.0f);
}

// Round 16
// 204.453 us; speedup vs baseline: 1.3196x; 1.0469x over previous
//
#include <hip/hip_runtime.h>
#include <cstdint>
#include <cmath>

#define DH 64
#define SQB 2048
#define SKVB 1024
#define DE 512

typedef _Float16 f16;
typedef _Float16 f16x8 __attribute__((ext_vector_type(8)));
typedef float f32x4 __attribute__((ext_vector_type(4)));
typedef float f32x16 __attribute__((ext_vector_type(16)));
typedef unsigned int u32;

#define MFMA32(A, B, C) __builtin_amdgcn_mfma_f32_32x32x16_f16(A, B, C, 0, 0, 0)

// ---------------------------------------------------------------------------
// async global->LDS 16B (wave-uniform LDS base + lane*16; global addr per-lane)
// ---------------------------------------------------------------------------
__device__ __forceinline__ void gl16(const f16* g, f16* l) {
  __builtin_amdgcn_global_load_lds(
      (const __attribute__((address_space(1))) u32*)g,
      (__attribute__((address_space(3))) u32*)l, 16, 0, 0);
}

// ---------------------------------------------------------------------------
// split helpers
// ---------------------------------------------------------------------------
__device__ __forceinline__ void do_split(const float* __restrict__ in,
                                         f16* __restrict__ hi, f16* __restrict__ lo,
                                         int i, float scale) {
  float4 v = ((const float4*)in)[i];
  v.x *= scale; v.y *= scale; v.z *= scale; v.w *= scale;
  f16 h0 = (f16)v.x, h1 = (f16)v.y, h2 = (f16)v.z, h3 = (f16)v.w;
  f16 l0 = (f16)(v.x - (float)h0), l1 = (f16)(v.y - (float)h1);
  f16 l2 = (f16)(v.z - (float)h2), l3 = (f16)(v.w - (float)h3);
  f16 hb[4] = {h0, h1, h2, h3};
  f16 lb[4] = {l0, l1, l2, l3};
  ((uint2*)hi)[i] = *(const uint2*)hb;
  ((uint2*)lo)[i] = *(const uint2*)lb;
}

// y only (x-split is fused into Q-proj staging)
__global__ __launch_bounds__(256)
void split1(const float* __restrict__ a, f16* __restrict__ ah, f16* __restrict__ al, int na) {
  const int i = blockIdx.x * 256 + threadIdx.x;
  if (i < na) do_split(a, ah, al, i, 1.0f);
}

// all four weights in one launch
__global__ __launch_bounds__(256)
void split4(const float* __restrict__ a, f16* __restrict__ ah, f16* __restrict__ al, int na, float sa,
            const float* __restrict__ b, f16* __restrict__ bh, f16* __restrict__ bl, int nb, float sb,
            const float* __restrict__ c, f16* __restrict__ ch, f16* __restrict__ cl, int nc, float sc,
            const float* __restrict__ d, f16* __restrict__ dh, f16* __restrict__ dl, int nd, float sd) {
  int i = blockIdx.x * 256 + threadIdx.x;
  if (i < na) { do_split(a, ah, al, i, sa); return; }
  i -= na;
  if (i < nb) { do_split(b, bh, bl, i, sb); return; }
  i -= nb;
  if (i < nc) { do_split(c, ch, cl, i, sc); return; }
  i -= nc;
  if (i < nd) do_split(d, dh, dl, i, sd);
}

// ---------------------------------------------------------------------------
// MFMA f16 GEMM — R4-validated math. W staged via global_load_lds(16) with
// pre-swizzled source. A staged either the same way (AFP32=0) or, for
// AFP32=1, reg-staged from fp32 with in-register hi/lo split (bit-identical
// LDS image to the pre-split path; eliminates the x-split kernel pass).
// Double-buffered, one barrier per K-step.
// OUT=0: C fp32. OUT=1: split-f16 pair of (C * oscale).
// ---------------------------------------------------------------------------
template <int NSPLIT, int OUT, int AFP32>
__global__ __launch_bounds__(256, NSPLIT == 3 ? 2 : 4)
void gemm_f16(const f16* __restrict__ Ah, const f16* __restrict__ Al,
              const float* __restrict__ Af,
              const f16* __restrict__ Wh, const f16* __restrict__ Wl,
              const float* __restrict__ bias, float* __restrict__ C,
              f16* __restrict__ Ch, f16* __restrict__ Cl,
              int M, int N, int K, float inv, float oscale) {
  constexpr int NPART = (NSPLIT == 3) ? 4 : 2;
  __shared__ f16 smem[2][NPART * 4096];   // parts: As, Ws, (Als, Wls)

  const int tid = threadIdx.x;
  const int w = tid >> 6;
  const int l = tid & 63;
  const int wm = w >> 1, wn = w & 1;
  const int m0 = blockIdx.y * 128;
  const int n0 = blockIdx.x * 128;

  const f16* gA  = AFP32 ? nullptr : Ah + (size_t)m0 * K;
  const f16* gW  = Wh + (size_t)n0 * K;
  const f16* gAl = (NSPLIT == 3 && !AFP32) ? Al + (size_t)m0 * K : nullptr;
  const f16* gWl = (NSPLIT == 3) ? Wl + (size_t)n0 * K : nullptr;

  const int fbase = (l & 15) * 32 + (((l >> 4) ^ (l & 3)) * 8);
  const int fA = wm * 2048 + fbase;
  const int fW = wn * 2048 + fbase;

  const int s0   = w * 128 + l;
  const int dl0  = (w * 128) * 8;
  const int dl1  = (w * 128 + 64) * 8;

  // slot geometry (both slots): srow = s>>2, schk = s&3, source chunk
  // pre-swizzled so LDS image matches the fragment-read XOR.
  const int srow0 = s0 >> 2,        schk0 = s0 & 3;
  const int srow1 = (s0 + 64) >> 2, schk1 = (s0 + 64) & 3;
  const int kswz0 = (schk0 ^ (srow0 & 3)) * 8;
  const int kswz1 = (schk1 ^ (srow1 & 3)) * 8;

  f32x4 acc[4][4] = {};
  float4 ra0, ra1, rb0, rb1;   // AFP32 staging regs

  auto loadA = [&](int k0) {
    const float* p0 = Af + (size_t)(m0 + srow0) * K + (k0 + kswz0);
    ra0 = *(const float4*)p0;
    ra1 = *(const float4*)(p0 + 4);
    const float* p1 = Af + (size_t)(m0 + srow1) * K + (k0 + kswz1);
    rb0 = *(const float4*)p1;
    rb1 = *(const float4*)(p1 + 4);
  };

  auto writeA = [&](int bsel) {
    f16 h[8], lo[8];
    float v0[8] = {ra0.x, ra0.y, ra0.z, ra0.w, ra1.x, ra1.y, ra1.z, ra1.w};
#pragma unroll
    for (int i = 0; i < 8; ++i) { h[i] = (f16)v0[i]; lo[i] = (f16)(v0[i] - (float)h[i]); }
    *(uint4*)&smem[bsel][s0 * 8] = *(const uint4*)h;
    *(uint4*)&smem[bsel][8192 + s0 * 8] = *(const uint4*)lo;
    float v1[8] = {rb0.x, rb0.y, rb0.z, rb0.w, rb1.x, rb1.y, rb1.z, rb1.w};
#pragma unroll
    for (int i = 0; i < 8; ++i) { h[i] = (f16)v1[i]; lo[i] = (f16)(v1[i] - (float)h[i]); }
    *(uint4*)&smem[bsel][(s0 + 64) * 8] = *(const uint4*)h;
    *(uint4*)&smem[bsel][8192 + (s0 + 64) * 8] = *(const uint4*)lo;
  };

  auto stage = [&](int k0, int bsel) {
    // W (always gl16); A too when !AFP32
    {
      const size_t go = (size_t)srow0 * K + (k0 + kswz0);
      gl16(gW + go, &smem[bsel][4096 + dl0]);
      if constexpr (NSPLIT == 3) gl16(gWl + go, &smem[bsel][12288 + dl0]);
      if constexpr (!AFP32) {
        gl16(gA + go, &smem[bsel][dl0]);
        if constexpr (NSPLIT == 3) gl16(gAl + go, &smem[bsel][8192 + dl0]);
      }
    }
    {
      const size_t go = (size_t)srow1 * K + (k0 + kswz1);
      gl16(gW + go, &smem[bsel][4096 + dl1]);
      if constexpr (NSPLIT == 3) gl16(gWl + go, &smem[bsel][12288 + dl1]);
      if constexpr (!AFP32) {
        gl16(gA + go, &smem[bsel][dl1]);
        if constexpr (NSPLIT == 3) gl16(gAl + go, &smem[bsel][8192 + dl1]);
      }
    }
  };

  // prologue
  if constexpr (AFP32) loadA(0);
  stage(0, 0);
  if constexpr (AFP32) writeA(0);
  __syncthreads();
  int buf = 0;

  for (int k0 = 0; k0 < K; k0 += 32) {
    const bool more = (k0 + 32 < K);
    if (more) {
      if constexpr (AFP32) loadA(k0 + 32);
      stage(k0 + 32, buf ^ 1);
    }

    const f16* Ls = smem[buf];
    f16x8 ah[4], wh[4], al[4], wl[4];
#pragma unroll
    for (int i = 0; i < 4; ++i) ah[i] = *(const f16x8*)&Ls[fA + i * 512];
#pragma unroll
    for (int j = 0; j < 4; ++j) wh[j] = *(const f16x8*)&Ls[4096 + fW + j * 512];
    if constexpr (NSPLIT == 3) {
#pragma unroll
      for (int i = 0; i < 4; ++i) al[i] = *(const f16x8*)&Ls[8192 + fA + i * 512];
#pragma unroll
      for (int j = 0; j < 4; ++j) wl[j] = *(const f16x8*)&Ls[12288 + fW + j * 512];
    }

#pragma unroll
    for (int i = 0; i < 4; ++i)
#pragma unroll
      for (int j = 0; j < 4; ++j)
        acc[i][j] = __builtin_amdgcn_mfma_f32_16x16x32_f16(ah[i], wh[j], acc[i][j], 0, 0, 0);
    if constexpr (NSPLIT == 3) {
#pragma unroll
      for (int i = 0; i < 4; ++i)
#pragma unroll
        for (int j = 0; j < 4; ++j)
          acc[i][j] = __builtin_amdgcn_mfma_f32_16x16x32_f16(ah[i], wl[j], acc[i][j], 0, 0, 0);
#pragma unroll
      for (int i = 0; i < 4; ++i)
#pragma unroll
        for (int j = 0; j < 4; ++j)
          acc[i][j] = __builtin_amdgcn_mfma_f32_16x16x32_f16(al[i], wh[j], acc[i][j], 0, 0, 0);
    }

    if (more) {
      if constexpr (AFP32) writeA(buf ^ 1);
    }
    __syncthreads();
    buf ^= 1;
  }

  const int rr = (l >> 4) * 4;
  const int cc = l & 15;
#pragma unroll
  for (int j = 0; j < 4; ++j) {
    const int n = n0 + wn * 64 + j * 16 + cc;
    const float bv = bias[n];
#pragma unroll
    for (int i = 0; i < 4; ++i) {
      const int m = m0 + wm * 64 + i * 16 + rr;
#pragma unroll
      for (int r = 0; r < 4; ++r) {
        const float val = acc[i][j][r] * inv + bv;
        if constexpr (OUT == 0) {
          C[(size_t)(m + r) * N + n] = val;
        } else {
          const float sv = val * oscale;
          const f16 hh = (f16)sv;
          const f16 ll = (f16)(sv - (float)hh);
          Ch[(size_t)(m + r) * N + n] = hh;
          Cl[(size_t)(m + r) * N + n] = ll;
        }
      }
    }
  }
}

// ---------------------------------------------------------------------------
// Canonical split-3 QK^T accumulation for one 32x32 tile. Same op order in
// main loop and slow-path recompute => bit-identical results.
// ---------------------------------------------------------------------------
__device__ __forceinline__ f32x16 qk_accum(const f16x8 ah[4], const f16x8 al[4],
                                           const f16x8 qh_[4], const f16x8 ql_[4]) {
  f32x16 ca = (f32x16){};
  f32x16 cb = (f32x16){};
  ca = MFMA32(ah[0], qh_[0], ca);  cb = MFMA32(ah[1], qh_[1], cb);
  ca = MFMA32(ah[2], qh_[2], ca);  cb = MFMA32(ah[3], qh_[3], cb);
  ca = MFMA32(al[0], qh_[0], ca);  cb = MFMA32(al[1], qh_[1], cb);
  ca = MFMA32(al[2], qh_[2], ca);  cb = MFMA32(al[3], qh_[3], cb);
  ca = MFMA32(ah[0], ql_[0], ca);  cb = MFMA32(ah[1], ql_[1], cb);
  ca = MFMA32(ah[2], ql_[2], ca);  cb = MFMA32(ah[3], ql_[3], cb);
  return ca + cb;
}

__device__ __forceinline__ f32x16 qk_tile_global(const f16* __restrict__ kgh,
                                                 const f16* __restrict__ kgl,
                                                 int tt, int q5, int hi5,
                                                 const f16x8 qh_[4], const f16x8 ql_[4]) {
  const f16* kh = kgh + (size_t)(tt * 32 + q5) * DE + hi5 * 8;
  const f16* kl = kgl + (size_t)(tt * 32 + q5) * DE + hi5 * 8;
  f16x8 ah[4], al[4];
#pragma unroll
  for (int s = 0; s < 4; ++s) {
    ah[s] = *(const f16x8*)(kh + s * 16);
    al[s] = *(const f16x8*)(kl + s * 16);
  }
  return qk_accum(ah, al, qh_, ql_);
}

// ---------------------------------------------------------------------------
// Fused sparse attention v14 (FROZEN) — proven 86 µs configuration.
// ---------------------------------------------------------------------------
__global__ __launch_bounds__(256, 3)
void attn_v14(const f16* __restrict__ qhb, const f16* __restrict__ qlb,
              const f16* __restrict__ khb, const f16* __restrict__ klb,
              const float* __restrict__ vb, f16* __restrict__ ob) {
  __shared__ f16 Ks[2][2][4096];
  __shared__ float4 stat[4][32];
  __shared__ int   sidx[4][48];
  __shared__ float sp[4][48];
  __shared__ int   scnt[4][2];

  const int phys = blockIdx.x;
  const int bid = (phys & 7) * 128 + (phys >> 3);
  const int b  = bid >> 7;
  const int h  = (bid >> 4) & 7;
  const int qt = bid & 15;
  const int tid = threadIdx.x;
  const int w  = tid >> 6;
  const int l  = tid & 63;
  const int q5 = l & 31;
  const int hi5 = l >> 5;

  const float C2 = 1.44269504f / 4096.0f;

  const int qrow = qt * 128 + w * 32 + q5;
  const f16* qpb = qhb + (size_t)(b * SQB + qrow) * DE + h * DH + hi5 * 8;
  const f16* qpl = qlb + (size_t)(b * SQB + qrow) * DE + h * DH + hi5 * 8;
  f16x8 qh_[4], ql_[4];
#pragma unroll
  for (int s = 0; s < 4; ++s) {
    qh_[s] = *(const f16x8*)(qpb + s * 16);
    ql_[s] = *(const f16x8*)(qpl + s * 16);
  }

  const f16* kgh = khb + (size_t)(b * SKVB) * DE + h * DH;
  const f16* kgl = klb + (size_t)(b * SKVB) * DE + h * DH;

  const int skv0 = tid >> 3;
  const int sch  = tid & 7;
  const int d_off0 = skv0 * 64 + ((sch ^ (skv0 & 7)) * 8);
  const int d_off1 = (32 + skv0) * 64 + ((sch ^ (skv0 & 7)) * 8);

  {
    const f16* shp = kgh + (size_t)skv0 * DE + sch * 8;
    const f16* slp = kgl + (size_t)skv0 * DE + sch * 8;
    uint4 a0 = *(const uint4*)(shp);
    uint4 a1 = *(const uint4*)(shp + 32 * DE);
    uint4 b0 = *(const uint4*)(slp);
    uint4 b1 = *(const uint4*)(slp + 32 * DE);
    *(uint4*)&Ks[0][0][d_off0] = a0;
    *(uint4*)&Ks[0][0][d_off1] = a1;
    *(uint4*)&Ks[0][1][d_off0] = b0;
    *(uint4*)&Ks[0][1][d_off1] = b1;
  }
  __syncthreads();

  float m = -INFINITY, Z0 = 0.f, Z1 = 0.f, H0 = 0.f, H1 = 0.f;
  int mt = 0;
  bool tie = false;
  f32x16 best = (f32x16){};

  for (int t = 0; t < 16; ++t) {
    const int cur = t & 1;
    const int nxt = cur ^ 1;
    uint4 La0, La1, Lb0, Lb1;
    const bool more = (t + 1 < 16);
    if (more) {
      const f16* shp = kgh + (size_t)((t + 1) * 64 + skv0) * DE + sch * 8;
      const f16* slp = kgl + (size_t)((t + 1) * 64 + skv0) * DE + sch * 8;
      La0 = *(const uint4*)(shp);
      La1 = *(const uint4*)(shp + 32 * DE);
      Lb0 = *(const uint4*)(slp);
      Lb1 = *(const uint4*)(slp + 32 * DE);
    }
#pragma unroll
    for (int u = 0; u < 2; ++u) {
      const int kvl = u * 32 + q5;
      const int rowoff = kvl * 64;
      f16x8 ah[4], al[4];
#pragma unroll
      for (int s = 0; s < 4; ++s) {
        const int idx = rowoff + (((s * 2 + hi5) ^ (q5 & 7)) * 8);
        ah[s] = *(const f16x8*)&Ks[cur][0][idx];
        al[s] = *(const f16x8*)&Ks[cur][1][idx];
      }
      const f32x16 sv = qk_accum(ah, al, qh_, ql_);
      const float g0 = fmaxf(fmaxf(sv[0], sv[1]), sv[2]);
      const float g1 = fmaxf(fmaxf(sv[3], sv[4]), sv[5]);
      const float g2 = fmaxf(fmaxf(sv[6], sv[7]), sv[8]);
      const float g3 = fmaxf(fmaxf(sv[9], sv[10]), sv[11]);
      const float g4 = fmaxf(fmaxf(sv[12], sv[13]), sv[14]);
      const float ga = fmaxf(fmaxf(g0, g1), g2);
      const float gb = fmaxf(fmaxf(g3, g4), sv[15]);
      const float tmax = fmaxf(ga, gb);
#pragma unroll
      for (int r = 0; r < 16; r += 2) {
        const float s0 = sv[r];
        const float s1 = sv[r + 1];
        const float e0 = __builtin_amdgcn_exp2f(s0 * C2);
        const float e1 = __builtin_amdgcn_exp2f(s1 * C2);
        Z0 += e0;
        Z1 += e1;
        H0 = fmaf(e0, s0, H0);
        H1 = fmaf(e1, s1, H1);
      }
      const bool upd = (tmax > m);
      tie = upd ? false : (tie || (tmax == m));
      if (upd) { m = tmax; mt = t * 2 + u; }
#pragma unroll
      for (int r = 0; r < 16; ++r) best[r] = upd ? sv[r] : best[r];
    }
    if (more) {
      *(uint4*)&Ks[nxt][0][d_off0] = La0;
      *(uint4*)&Ks[nxt][0][d_off1] = La1;
      *(uint4*)&Ks[nxt][1][d_off0] = Lb0;
      *(uint4*)&Ks[nxt][1][d_off1] = Lb1;
    }
    __syncthreads();
  }

  float Z = Z0 + Z1;
  float H = H0 + H1;
  const float mo = __shfl_xor(m, 32);
  const int tieo = __shfl_xor(tie ? 1 : 0, 32);
  Z += __shfl_xor(Z, 32);
  H += __shfl_xor(H, 32);
  const float mc = fmaxf(m, mo);
  const bool tiec = (m > mo) ? tie : ((mo > m) ? (tieo != 0) : (tie || tieo != 0));

  int c = 0, p1 = -1, p2 = -1;
#pragma unroll
  for (int r = 0; r < 16; ++r) {
    if (best[r] == mc) {
      const int pos = mt * 32 + (r & 3) + 8 * (r >> 2) + 4 * hi5;
      p2 = (c == 1) ? pos : p2;
      p1 = (c == 0) ? pos : p1;
      ++c;
    }
  }
  const int co  = __shfl_xor(c, 32);
  const int p1o = __shfl_xor(p1, 32);
  const int p2o = __shfl_xor(p2, 32);
  const int ct = c + co;
  const int pa = (c > 0) ? p1 : p1o;
  const int pb = (c >= 2) ? p2 : ((c == 1) ? ((co > 0) ? p1o : -1)
                                           : ((co >= 2) ? p2o : -1));

  const float E = __logf(Z) - (H * (1.0f / 4096.0f)) / Z;
  int tk = (int)(32.0f * (1.0f - E));
  tk = tk < 1 ? 1 : (tk > 32 ? 32 : tk);
  const bool slowRow = (tk > 1) || tiec || (ct > 2);
  const float zeps = 1e-8f * Z * __builtin_amdgcn_exp2f(-mc * C2);
  const float wt = 1.0f / ((float)ct + zeps);

  if (hi5 == 0)
    stat[w][q5] = make_float4(slowRow ? -1.0f : wt,
                              __int_as_float(pa),
                              __int_as_float(ct == 2 ? pb : -1),
                              (float)ct);

  {
    const size_t obase = (size_t)(b * SQB + qt * 128 + w * 32) * DE + h * DH + l;
    const float* vB = vb + (size_t)(b * SKVB) * DE + h * DH + l;
    for (int r = 0; r < 32; ++r) {
      const float4 st = stat[w][r];
      if (st.x >= 0.f) {
        const int ppa = __float_as_int(st.y);
        const int ppb = __float_as_int(st.z);
        float acc = vB[(size_t)ppa * DE];
        if (ppb >= 0) acc += vB[(size_t)ppb * DE];
        ob[obase + (size_t)r * DE] = (f16)(acc * st.x);
      }
    }
  }

  {
    unsigned long long sb = __ballot(slowRow && hi5 == 0);
    while (sb != 0ull) {
      const int rr = (int)__builtin_ctzll(sb);
      sb &= sb - 1;
      const float mr = __shfl(mc, rr);
      const int tkr  = __shfl(tk, rr);
      const float Zr = __shfl(Z, rr);
      float thr = mr;
      float rem = (float)tkr;
      float cand = mr;
      int guard = 0;
      bool done = false;
      while (!done && guard < 40) {
        ++guard;
        float cf = 0.f, nmx = -INFINITY;
        for (int tt = 0; tt < 32; ++tt) {
          const f32x16 sv = qk_tile_global(kgh, kgl, tt, q5, hi5, qh_, ql_);
          if (q5 == rr) {
#pragma unroll
            for (int r = 0; r < 16; ++r) {
              cf += (sv[r] == cand) ? 1.f : 0.f;
              nmx = (sv[r] < cand) ? fmaxf(nmx, sv[r]) : nmx;
            }
          }
        }
        cf += __shfl_xor(cf, 32);
        nmx = fmaxf(nmx, __shfl_xor(nmx, 32));
        const float cfr = __shfl(cf, rr);
        const float nmr = __shfl(nmx, rr);
        if (cfr >= rem) { thr = cand; done = true; }
        else { rem -= cfr; cand = nmr; }
      }
      int myc = 0;
      for (int tt = 0; tt < 32; ++tt) {
        const f32x16 sv = qk_tile_global(kgh, kgl, tt, q5, hi5, qh_, ql_);
        if (q5 == rr) {
#pragma unroll
          for (int r = 0; r < 16; ++r) {
            if (sv[r] >= thr && myc < 24) {
              sidx[w][hi5 * 24 + myc] = tt * 32 + (r & 3) + 8 * (r >> 2) + 4 * hi5;
              sp[w][hi5 * 24 + myc] = __builtin_amdgcn_exp2f((sv[r] - mr) * C2);
              ++myc;
            }
          }
        }
      }
      if (q5 == rr) scnt[w][hi5] = myc;
      int c0 = scnt[w][0]; c0 = c0 > 24 ? 24 : c0;
      int c1 = scnt[w][1]; c1 = c1 > 24 ? 24 : c1;
      float acc = 0.f, ps = 0.f;
      const float* vB = vb + (size_t)(b * SKVB) * DE + h * DH + l;
      for (int e = 0; e < c0; ++e) {
        const int kv = sidx[w][e]; const float p = sp[w][e];
        ps += p; acc = fmaf(p, vB[(size_t)kv * DE], acc);
      }
      for (int e = 0; e < c1; ++e) {
        const int kv = sidx[w][24 + e]; const float p = sp[w][24 + e];
        ps += p; acc = fmaf(p, vB[(size_t)kv * DE], acc);
      }
      const float zepsr = 1e-8f * Zr * __builtin_amdgcn_exp2f(-mr * C2);
      const float o = acc / (ps + zepsr);
      ob[(size_t)(b * SQB + qt * 128 + w * 32 + rr) * DE + h * DH + l] = (f16)o;
    }
  }
}

// ---------------------------------------------------------------------------
extern "C" void kernel_launch(void* const* d_in, const int* in_sizes, int n_in,
                              void* d_out, int out_size, void* d_ws, size_t ws_size,
                              hipStream_t stream) {
  const float* x  = (const float*)d_in[0];
  const float* y  = (const float*)d_in[1];
  const float* wq = (const float*)d_in[2];
  const float* bq = (const float*)d_in[3];
  const float* wk = (const float*)d_in[4];
  const float* bk = (const float*)d_in[5];
  const float* wv = (const float*)d_in[6];
  const float* bv = (const float*)d_in[7];
  const float* wo = (const float*)d_in[8];
  const float* bo = (const float*)d_in[9];
  float* out = (float*)d_out;

  char* ws = (char*)d_ws;
  const size_t MiB = 1048576;

  f16* yh  = (f16*)(ws + 32 * MiB);            // 12
  f16* yl  = (f16*)(ws + 44 * MiB);            // 12
  f16* qh  = (f16*)(ws + 56 * MiB);            // 16
  f16* ql  = (f16*)(ws + 72 * MiB);            // 16
  f16* kh  = (f16*)(ws + 88 * MiB);            // 8
  f16* kl  = (f16*)(ws + 96 * MiB);            // 8
  float* v = (float*)(ws + 104 * MiB);         // 16 (f32)
  f16* ao  = (f16*)(ws + 120 * MiB);           // 16
  f16* wqh = (f16*)(ws + 136 * MiB);
  f16* wql = (f16*)(ws + 136 * MiB + 524288);
  f16* wkh = (f16*)(ws + 137 * MiB);
  f16* wkl = (f16*)(ws + 137 * MiB + 786432);
  f16* wvh = (f16*)(ws + 138 * MiB + 524288);
  f16* wvl = (f16*)(ws + 139 * MiB + 262144);
  f16* woh = (f16*)(ws + 140 * MiB);
  f16* wol = (f16*)(ws + 140 * MiB + 524288);

  dim3 blk(256);
  const float WS = 2048.0f, IWS = 1.0f / 2048.0f;

  // y split only (x-split fused into Q-proj staging)
  split1<<<dim3(6144), blk, 0, stream>>>(y, yh, yl, 1572864);
  split4<<<dim3(1280), blk, 0, stream>>>(wq, wqh, wql, 65536, WS,
                                         wk, wkh, wkl, 98304, WS,
                                         wv, wvh, wvl, 98304, 1.0f,
                                         wo, woh, wol, 65536, 1.0f);

  // Q-proj: A = x fp32, in-register split (bit-identical to pre-split path)
  gemm_f16<3, 1, 1><<<dim3(4, 128), blk, 0, stream>>>(nullptr, nullptr, x,
      wqh, wql, bq, nullptr, qh, ql, 16384, 512, 512, IWS, 8.0f);
  // K-proj -> split pair scaled x64
  gemm_f16<3, 1, 0><<<dim3(4, 64), blk, 0, stream>>>(yh, yl, nullptr,
      wkh, wkl, bk, nullptr, kh, kl, 8192, 512, 768, IWS, 64.0f);
  // V-proj -> f32
  gemm_f16<1, 0, 0><<<dim3(4, 64), blk, 0, stream>>>(yh, nullptr, nullptr,
      wvh, nullptr, bv, v, nullptr, nullptr, 8192, 512, 768, 1.0f, 1.0f);

  attn_v14<<<dim3(1024), blk, 0, stream>>>(qh, ql, kh, kl, v, ao);

  // O-proj
  gemm_f16<1, 0, 0><<<dim3(4, 128), blk, 0, stream>>>(ao, nullptr, nullptr,
      woh, nullptr, bo, out, nullptr, nullptr, 16384, 512, 512, 1.0f, 1.0f);
}

// Round 17
// 204.252 us; speedup vs baseline: 1.3209x; 1.0010x over previous
//
#include <hip/hip_runtime.h>
#include <cstdint>
#include <cmath>

#define DH 64
#define SQB 2048
#define SKVB 1024
#define DE 512

typedef _Float16 f16;
typedef _Float16 f16x8 __attribute__((ext_vector_type(8)));
typedef float f32x4 __attribute__((ext_vector_type(4)));
typedef float f32x16 __attribute__((ext_vector_type(16)));
typedef unsigned int u32;

#define MFMA32(A, B, C) __builtin_amdgcn_mfma_f32_32x32x16_f16(A, B, C, 0, 0, 0)

// ---------------------------------------------------------------------------
// async global->LDS 16B (wave-uniform LDS base + lane*16; global addr per-lane)
// ---------------------------------------------------------------------------
__device__ __forceinline__ void gl16(const f16* g, f16* l) {
  __builtin_amdgcn_global_load_lds(
      (const __attribute__((address_space(1))) u32*)g,
      (__attribute__((address_space(3))) u32*)l, 16, 0, 0);
}

// ---------------------------------------------------------------------------
// split helper (weights only now)
// ---------------------------------------------------------------------------
__device__ __forceinline__ void do_split(const float* __restrict__ in,
                                         f16* __restrict__ hi, f16* __restrict__ lo,
                                         int i, float scale) {
  float4 v = ((const float4*)in)[i];
  v.x *= scale; v.y *= scale; v.z *= scale; v.w *= scale;
  f16 h0 = (f16)v.x, h1 = (f16)v.y, h2 = (f16)v.z, h3 = (f16)v.w;
  f16 l0 = (f16)(v.x - (float)h0), l1 = (f16)(v.y - (float)h1);
  f16 l2 = (f16)(v.z - (float)h2), l3 = (f16)(v.w - (float)h3);
  f16 hb[4] = {h0, h1, h2, h3};
  f16 lb[4] = {l0, l1, l2, l3};
  ((uint2*)hi)[i] = *(const uint2*)hb;
  ((uint2*)lo)[i] = *(const uint2*)lb;
}

// all four weights in one launch
__global__ __launch_bounds__(256)
void split4(const float* __restrict__ a, f16* __restrict__ ah, f16* __restrict__ al, int na, float sa,
            const float* __restrict__ b, f16* __restrict__ bh, f16* __restrict__ bl, int nb, float sb,
            const float* __restrict__ c, f16* __restrict__ ch, f16* __restrict__ cl, int nc, float sc,
            const float* __restrict__ d, f16* __restrict__ dh, f16* __restrict__ dl, int nd, float sd) {
  int i = blockIdx.x * 256 + threadIdx.x;
  if (i < na) { do_split(a, ah, al, i, sa); return; }
  i -= na;
  if (i < nb) { do_split(b, bh, bl, i, sb); return; }
  i -= nb;
  if (i < nc) { do_split(c, ch, cl, i, sc); return; }
  i -= nc;
  if (i < nd) do_split(d, dh, dl, i, sd);
}

// ---------------------------------------------------------------------------
// MFMA f16 GEMM — R4-validated math. W staged via global_load_lds(16) with
// pre-swizzled source. A staged the same way (AFP32=0) or, for AFP32=1,
// reg-staged from fp32 with in-register hi/lo split (bit-identical LDS
// image to the pre-split path; eliminates the activation-split kernels).
// Double-buffered, one barrier per K-step.
// OUT=0: C fp32. OUT=1: split-f16 pair of (C * oscale).
// ---------------------------------------------------------------------------
template <int NSPLIT, int OUT, int AFP32>
__global__ __launch_bounds__(256, NSPLIT == 3 ? 2 : 4)
void gemm_f16(const f16* __restrict__ Ah, const f16* __restrict__ Al,
              const float* __restrict__ Af,
              const f16* __restrict__ Wh, const f16* __restrict__ Wl,
              const float* __restrict__ bias, float* __restrict__ C,
              f16* __restrict__ Ch, f16* __restrict__ Cl,
              int M, int N, int K, float inv, float oscale) {
  constexpr int NPART = (NSPLIT == 3) ? 4 : 2;
  __shared__ f16 smem[2][NPART * 4096];   // parts: As, Ws, (Als, Wls)
  constexpr int WOFF  = (NSPLIT == 3) ? 4096 : 4096;
  constexpr int ALOFF = 8192;             // NSPLIT==3 only
  constexpr int WLOFF = 12288;            // NSPLIT==3 only

  const int tid = threadIdx.x;
  const int w = tid >> 6;
  const int l = tid & 63;
  const int wm = w >> 1, wn = w & 1;
  const int m0 = blockIdx.y * 128;
  const int n0 = blockIdx.x * 128;

  const f16* gA  = AFP32 ? nullptr : Ah + (size_t)m0 * K;
  const f16* gW  = Wh + (size_t)n0 * K;
  const f16* gAl = (NSPLIT == 3 && !AFP32) ? Al + (size_t)m0 * K : nullptr;
  const f16* gWl = (NSPLIT == 3) ? Wl + (size_t)n0 * K : nullptr;

  const int fbase = (l & 15) * 32 + (((l >> 4) ^ (l & 3)) * 8);
  const int fA = wm * 2048 + fbase;
  const int fW = wn * 2048 + fbase;

  const int s0   = w * 128 + l;
  const int dl0  = (w * 128) * 8;
  const int dl1  = (w * 128 + 64) * 8;

  // slot geometry: srow = s>>2, schk = s&3, source chunk pre-swizzled so
  // the LDS image matches the fragment-read XOR.
  const int srow0 = s0 >> 2,        schk0 = s0 & 3;
  const int srow1 = (s0 + 64) >> 2, schk1 = (s0 + 64) & 3;
  const int kswz0 = (schk0 ^ (srow0 & 3)) * 8;
  const int kswz1 = (schk1 ^ (srow1 & 3)) * 8;

  f32x4 acc[4][4] = {};
  float4 ra0, ra1, rb0, rb1;   // AFP32 staging regs

  auto loadA = [&](int k0) {
    const float* p0 = Af + (size_t)(m0 + srow0) * K + (k0 + kswz0);
    ra0 = *(const float4*)p0;
    ra1 = *(const float4*)(p0 + 4);
    const float* p1 = Af + (size_t)(m0 + srow1) * K + (k0 + kswz1);
    rb0 = *(const float4*)p1;
    rb1 = *(const float4*)(p1 + 4);
  };

  auto writeA = [&](int bsel) {
    f16 h[8], lo[8];
    float v0[8] = {ra0.x, ra0.y, ra0.z, ra0.w, ra1.x, ra1.y, ra1.z, ra1.w};
#pragma unroll
    for (int i = 0; i < 8; ++i) { h[i] = (f16)v0[i]; lo[i] = (f16)(v0[i] - (float)h[i]); }
    *(uint4*)&smem[bsel][s0 * 8] = *(const uint4*)h;
    if constexpr (NSPLIT == 3) *(uint4*)&smem[bsel][ALOFF + s0 * 8] = *(const uint4*)lo;
    float v1[8] = {rb0.x, rb0.y, rb0.z, rb0.w, rb1.x, rb1.y, rb1.z, rb1.w};
#pragma unroll
    for (int i = 0; i < 8; ++i) { h[i] = (f16)v1[i]; lo[i] = (f16)(v1[i] - (float)h[i]); }
    *(uint4*)&smem[bsel][(s0 + 64) * 8] = *(const uint4*)h;
    if constexpr (NSPLIT == 3) *(uint4*)&smem[bsel][ALOFF + (s0 + 64) * 8] = *(const uint4*)lo;
  };

  auto stage = [&](int k0, int bsel) {
    {
      const size_t go = (size_t)srow0 * K + (k0 + kswz0);
      gl16(gW + go, &smem[bsel][WOFF + dl0]);
      if constexpr (NSPLIT == 3) gl16(gWl + go, &smem[bsel][WLOFF + dl0]);
      if constexpr (!AFP32) {
        gl16(gA + go, &smem[bsel][dl0]);
        if constexpr (NSPLIT == 3) gl16(gAl + go, &smem[bsel][ALOFF + dl0]);
      }
    }
    {
      const size_t go = (size_t)srow1 * K + (k0 + kswz1);
      gl16(gW + go, &smem[bsel][WOFF + dl1]);
      if constexpr (NSPLIT == 3) gl16(gWl + go, &smem[bsel][WLOFF + dl1]);
      if constexpr (!AFP32) {
        gl16(gA + go, &smem[bsel][dl1]);
        if constexpr (NSPLIT == 3) gl16(gAl + go, &smem[bsel][ALOFF + dl1]);
      }
    }
  };

  // prologue
  if constexpr (AFP32) loadA(0);
  stage(0, 0);
  if constexpr (AFP32) writeA(0);
  __syncthreads();
  int buf = 0;

  for (int k0 = 0; k0 < K; k0 += 32) {
    const bool more = (k0 + 32 < K);
    if (more) {
      if constexpr (AFP32) loadA(k0 + 32);
      stage(k0 + 32, buf ^ 1);
    }

    const f16* Ls = smem[buf];
    f16x8 ah[4], wh[4], al[4], wl[4];
#pragma unroll
    for (int i = 0; i < 4; ++i) ah[i] = *(const f16x8*)&Ls[fA + i * 512];
#pragma unroll
    for (int j = 0; j < 4; ++j) wh[j] = *(const f16x8*)&Ls[WOFF + fW + j * 512];
    if constexpr (NSPLIT == 3) {
#pragma unroll
      for (int i = 0; i < 4; ++i) al[i] = *(const f16x8*)&Ls[ALOFF + fA + i * 512];
#pragma unroll
      for (int j = 0; j < 4; ++j) wl[j] = *(const f16x8*)&Ls[WLOFF + fW + j * 512];
    }

#pragma unroll
    for (int i = 0; i < 4; ++i)
#pragma unroll
      for (int j = 0; j < 4; ++j)
        acc[i][j] = __builtin_amdgcn_mfma_f32_16x16x32_f16(ah[i], wh[j], acc[i][j], 0, 0, 0);
    if constexpr (NSPLIT == 3) {
#pragma unroll
      for (int i = 0; i < 4; ++i)
#pragma unroll
        for (int j = 0; j < 4; ++j)
          acc[i][j] = __builtin_amdgcn_mfma_f32_16x16x32_f16(ah[i], wl[j], acc[i][j], 0, 0, 0);
#pragma unroll
      for (int i = 0; i < 4; ++i)
#pragma unroll
        for (int j = 0; j < 4; ++j)
          acc[i][j] = __builtin_amdgcn_mfma_f32_16x16x32_f16(al[i], wh[j], acc[i][j], 0, 0, 0);
    }

    if (more) {
      if constexpr (AFP32) writeA(buf ^ 1);
    }
    __syncthreads();
    buf ^= 1;
  }

  const int rr = (l >> 4) * 4;
  const int cc = l & 15;
#pragma unroll
  for (int j = 0; j < 4; ++j) {
    const int n = n0 + wn * 64 + j * 16 + cc;
    const float bv = bias[n];
#pragma unroll
    for (int i = 0; i < 4; ++i) {
      const int m = m0 + wm * 64 + i * 16 + rr;
#pragma unroll
      for (int r = 0; r < 4; ++r) {
        const float val = acc[i][j][r] * inv + bv;
        if constexpr (OUT == 0) {
          C[(size_t)(m + r) * N + n] = val;
        } else {
          const float sv = val * oscale;
          const f16 hh = (f16)sv;
          const f16 ll = (f16)(sv - (float)hh);
          Ch[(size_t)(m + r) * N + n] = hh;
          Cl[(size_t)(m + r) * N + n] = ll;
        }
      }
    }
  }
}

// ---------------------------------------------------------------------------
// Canonical split-3 QK^T accumulation for one 32x32 tile. Same op order in
// main loop and slow-path recompute => bit-identical results.
// ---------------------------------------------------------------------------
__device__ __forceinline__ f32x16 qk_accum(const f16x8 ah[4], const f16x8 al[4],
                                           const f16x8 qh_[4], const f16x8 ql_[4]) {
  f32x16 ca = (f32x16){};
  f32x16 cb = (f32x16){};
  ca = MFMA32(ah[0], qh_[0], ca);  cb = MFMA32(ah[1], qh_[1], cb);
  ca = MFMA32(ah[2], qh_[2], ca);  cb = MFMA32(ah[3], qh_[3], cb);
  ca = MFMA32(al[0], qh_[0], ca);  cb = MFMA32(al[1], qh_[1], cb);
  ca = MFMA32(al[2], qh_[2], ca);  cb = MFMA32(al[3], qh_[3], cb);
  ca = MFMA32(ah[0], ql_[0], ca);  cb = MFMA32(ah[1], ql_[1], cb);
  ca = MFMA32(ah[2], ql_[2], ca);  cb = MFMA32(ah[3], ql_[3], cb);
  return ca + cb;
}

__device__ __forceinline__ f32x16 qk_tile_global(const f16* __restrict__ kgh,
                                                 const f16* __restrict__ kgl,
                                                 int tt, int q5, int hi5,
                                                 const f16x8 qh_[4], const f16x8 ql_[4]) {
  const f16* kh = kgh + (size_t)(tt * 32 + q5) * DE + hi5 * 8;
  const f16* kl = kgl + (size_t)(tt * 32 + q5) * DE + hi5 * 8;
  f16x8 ah[4], al[4];
#pragma unroll
  for (int s = 0; s < 4; ++s) {
    ah[s] = *(const f16x8*)(kh + s * 16);
    al[s] = *(const f16x8*)(kl + s * 16);
  }
  return qk_accum(ah, al, qh_, ql_);
}

// ---------------------------------------------------------------------------
// Fused sparse attention v14 (FROZEN) — proven 86 µs configuration.
// ---------------------------------------------------------------------------
__global__ __launch_bounds__(256, 3)
void attn_v14(const f16* __restrict__ qhb, const f16* __restrict__ qlb,
              const f16* __restrict__ khb, const f16* __restrict__ klb,
              const float* __restrict__ vb, f16* __restrict__ ob) {
  __shared__ f16 Ks[2][2][4096];
  __shared__ float4 stat[4][32];
  __shared__ int   sidx[4][48];
  __shared__ float sp[4][48];
  __shared__ int   scnt[4][2];

  const int phys = blockIdx.x;
  const int bid = (phys & 7) * 128 + (phys >> 3);
  const int b  = bid >> 7;
  const int h  = (bid >> 4) & 7;
  const int qt = bid & 15;
  const int tid = threadIdx.x;
  const int w  = tid >> 6;
  const int l  = tid & 63;
  const int q5 = l & 31;
  const int hi5 = l >> 5;

  const float C2 = 1.44269504f / 4096.0f;

  const int qrow = qt * 128 + w * 32 + q5;
  const f16* qpb = qhb + (size_t)(b * SQB + qrow) * DE + h * DH + hi5 * 8;
  const f16* qpl = qlb + (size_t)(b * SQB + qrow) * DE + h * DH + hi5 * 8;
  f16x8 qh_[4], ql_[4];
#pragma unroll
  for (int s = 0; s < 4; ++s) {
    qh_[s] = *(const f16x8*)(qpb + s * 16);
    ql_[s] = *(const f16x8*)(qpl + s * 16);
  }

  const f16* kgh = khb + (size_t)(b * SKVB) * DE + h * DH;
  const f16* kgl = klb + (size_t)(b * SKVB) * DE + h * DH;

  const int skv0 = tid >> 3;
  const int sch  = tid & 7;
  const int d_off0 = skv0 * 64 + ((sch ^ (skv0 & 7)) * 8);
  const int d_off1 = (32 + skv0) * 64 + ((sch ^ (skv0 & 7)) * 8);

  {
    const f16* shp = kgh + (size_t)skv0 * DE + sch * 8;
    const f16* slp = kgl + (size_t)skv0 * DE + sch * 8;
    uint4 a0 = *(const uint4*)(shp);
    uint4 a1 = *(const uint4*)(shp + 32 * DE);
    uint4 b0 = *(const uint4*)(slp);
    uint4 b1 = *(const uint4*)(slp + 32 * DE);
    *(uint4*)&Ks[0][0][d_off0] = a0;
    *(uint4*)&Ks[0][0][d_off1] = a1;
    *(uint4*)&Ks[0][1][d_off0] = b0;
    *(uint4*)&Ks[0][1][d_off1] = b1;
  }
  __syncthreads();

  float m = -INFINITY, Z0 = 0.f, Z1 = 0.f, H0 = 0.f, H1 = 0.f;
  int mt = 0;
  bool tie = false;
  f32x16 best = (f32x16){};

  for (int t = 0; t < 16; ++t) {
    const int cur = t & 1;
    const int nxt = cur ^ 1;
    uint4 La0, La1, Lb0, Lb1;
    const bool more = (t + 1 < 16);
    if (more) {
      const f16* shp = kgh + (size_t)((t + 1) * 64 + skv0) * DE + sch * 8;
      const f16* slp = kgl + (size_t)((t + 1) * 64 + skv0) * DE + sch * 8;
      La0 = *(const uint4*)(shp);
      La1 = *(const uint4*)(shp + 32 * DE);
      Lb0 = *(const uint4*)(slp);
      Lb1 = *(const uint4*)(slp + 32 * DE);
    }
#pragma unroll
    for (int u = 0; u < 2; ++u) {
      const int kvl = u * 32 + q5;
      const int rowoff = kvl * 64;
      f16x8 ah[4], al[4];
#pragma unroll
      for (int s = 0; s < 4; ++s) {
        const int idx = rowoff + (((s * 2 + hi5) ^ (q5 & 7)) * 8);
        ah[s] = *(const f16x8*)&Ks[cur][0][idx];
        al[s] = *(const f16x8*)&Ks[cur][1][idx];
      }
      const f32x16 sv = qk_accum(ah, al, qh_, ql_);
      const float g0 = fmaxf(fmaxf(sv[0], sv[1]), sv[2]);
      const float g1 = fmaxf(fmaxf(sv[3], sv[4]), sv[5]);
      const float g2 = fmaxf(fmaxf(sv[6], sv[7]), sv[8]);
      const float g3 = fmaxf(fmaxf(sv[9], sv[10]), sv[11]);
      const float g4 = fmaxf(fmaxf(sv[12], sv[13]), sv[14]);
      const float ga = fmaxf(fmaxf(g0, g1), g2);
      const float gb = fmaxf(fmaxf(g3, g4), sv[15]);
      const float tmax = fmaxf(ga, gb);
#pragma unroll
      for (int r = 0; r < 16; r += 2) {
        const float s0 = sv[r];
        const float s1 = sv[r + 1];
        const float e0 = __builtin_amdgcn_exp2f(s0 * C2);
        const float e1 = __builtin_amdgcn_exp2f(s1 * C2);
        Z0 += e0;
        Z1 += e1;
        H0 = fmaf(e0, s0, H0);
        H1 = fmaf(e1, s1, H1);
      }
      const bool upd = (tmax > m);
      tie = upd ? false : (tie || (tmax == m));
      if (upd) { m = tmax; mt = t * 2 + u; }
#pragma unroll
      for (int r = 0; r < 16; ++r) best[r] = upd ? sv[r] : best[r];
    }
    if (more) {
      *(uint4*)&Ks[nxt][0][d_off0] = La0;
      *(uint4*)&Ks[nxt][0][d_off1] = La1;
      *(uint4*)&Ks[nxt][1][d_off0] = Lb0;
      *(uint4*)&Ks[nxt][1][d_off1] = Lb1;
    }
    __syncthreads();
  }

  float Z = Z0 + Z1;
  float H = H0 + H1;
  const float mo = __shfl_xor(m, 32);
  const int tieo = __shfl_xor(tie ? 1 : 0, 32);
  Z += __shfl_xor(Z, 32);
  H += __shfl_xor(H, 32);
  const float mc = fmaxf(m, mo);
  const bool tiec = (m > mo) ? tie : ((mo > m) ? (tieo != 0) : (tie || tieo != 0));

  int c = 0, p1 = -1, p2 = -1;
#pragma unroll
  for (int r = 0; r < 16; ++r) {
    if (best[r] == mc) {
      const int pos = mt * 32 + (r & 3) + 8 * (r >> 2) + 4 * hi5;
      p2 = (c == 1) ? pos : p2;
      p1 = (c == 0) ? pos : p1;
      ++c;
    }
  }
  const int co  = __shfl_xor(c, 32);
  const int p1o = __shfl_xor(p1, 32);
  const int p2o = __shfl_xor(p2, 32);
  const int ct = c + co;
  const int pa = (c > 0) ? p1 : p1o;
  const int pb = (c >= 2) ? p2 : ((c == 1) ? ((co > 0) ? p1o : -1)
                                           : ((co >= 2) ? p2o : -1));

  const float E = __logf(Z) - (H * (1.0f / 4096.0f)) / Z;
  int tk = (int)(32.0f * (1.0f - E));
  tk = tk < 1 ? 1 : (tk > 32 ? 32 : tk);
  const bool slowRow = (tk > 1) || tiec || (ct > 2);
  const float zeps = 1e-8f * Z * __builtin_amdgcn_exp2f(-mc * C2);
  const float wt = 1.0f / ((float)ct + zeps);

  if (hi5 == 0)
    stat[w][q5] = make_float4(slowRow ? -1.0f : wt,
                              __int_as_float(pa),
                              __int_as_float(ct == 2 ? pb : -1),
                              (float)ct);

  {
    const size_t obase = (size_t)(b * SQB + qt * 128 + w * 32) * DE + h * DH + l;
    const float* vB = vb + (size_t)(b * SKVB) * DE + h * DH + l;
    for (int r = 0; r < 32; ++r) {
      const float4 st = stat[w][r];
      if (st.x >= 0.f) {
        const int ppa = __float_as_int(st.y);
        const int ppb = __float_as_int(st.z);
        float acc = vB[(size_t)ppa * DE];
        if (ppb >= 0) acc += vB[(size_t)ppb * DE];
        ob[obase + (size_t)r * DE] = (f16)(acc * st.x);
      }
    }
  }

  {
    unsigned long long sb = __ballot(slowRow && hi5 == 0);
    while (sb != 0ull) {
      const int rr = (int)__builtin_ctzll(sb);
      sb &= sb - 1;
      const float mr = __shfl(mc, rr);
      const int tkr  = __shfl(tk, rr);
      const float Zr = __shfl(Z, rr);
      float thr = mr;
      float rem = (float)tkr;
      float cand = mr;
      int guard = 0;
      bool done = false;
      while (!done && guard < 40) {
        ++guard;
        float cf = 0.f, nmx = -INFINITY;
        for (int tt = 0; tt < 32; ++tt) {
          const f32x16 sv = qk_tile_global(kgh, kgl, tt, q5, hi5, qh_, ql_);
          if (q5 == rr) {
#pragma unroll
            for (int r = 0; r < 16; ++r) {
              cf += (sv[r] == cand) ? 1.f : 0.f;
              nmx = (sv[r] < cand) ? fmaxf(nmx, sv[r]) : nmx;
            }
          }
        }
        cf += __shfl_xor(cf, 32);
        nmx = fmaxf(nmx, __shfl_xor(nmx, 32));
        const float cfr = __shfl(cf, rr);
        const float nmr = __shfl(nmx, rr);
        if (cfr >= rem) { thr = cand; done = true; }
        else { rem -= cfr; cand = nmr; }
      }
      int myc = 0;
      for (int tt = 0; tt < 32; ++tt) {
        const f32x16 sv = qk_tile_global(kgh, kgl, tt, q5, hi5, qh_, ql_);
        if (q5 == rr) {
#pragma unroll
          for (int r = 0; r < 16; ++r) {
            if (sv[r] >= thr && myc < 24) {
              sidx[w][hi5 * 24 + myc] = tt * 32 + (r & 3) + 8 * (r >> 2) + 4 * hi5;
              sp[w][hi5 * 24 + myc] = __builtin_amdgcn_exp2f((sv[r] - mr) * C2);
              ++myc;
            }
          }
        }
      }
      if (q5 == rr) scnt[w][hi5] = myc;
      int c0 = scnt[w][0]; c0 = c0 > 24 ? 24 : c0;
      int c1 = scnt[w][1]; c1 = c1 > 24 ? 24 : c1;
      float acc = 0.f, ps = 0.f;
      const float* vB = vb + (size_t)(b * SKVB) * DE + h * DH + l;
      for (int e = 0; e < c0; ++e) {
        const int kv = sidx[w][e]; const float p = sp[w][e];
        ps += p; acc = fmaf(p, vB[(size_t)kv * DE], acc);
      }
      for (int e = 0; e < c1; ++e) {
        const int kv = sidx[w][24 + e]; const float p = sp[w][24 + e];
        ps += p; acc = fmaf(p, vB[(size_t)kv * DE], acc);
      }
      const float zepsr = 1e-8f * Zr * __builtin_amdgcn_exp2f(-mr * C2);
      const float o = acc / (ps + zepsr);
      ob[(size_t)(b * SQB + qt * 128 + w * 32 + rr) * DE + h * DH + l] = (f16)o;
    }
  }
}

// ---------------------------------------------------------------------------
extern "C" void kernel_launch(void* const* d_in, const int* in_sizes, int n_in,
                              void* d_out, int out_size, void* d_ws, size_t ws_size,
                              hipStream_t stream) {
  const float* x  = (const float*)d_in[0];
  const float* y  = (const float*)d_in[1];
  const float* wq = (const float*)d_in[2];
  const float* bq = (const float*)d_in[3];
  const float* wk = (const float*)d_in[4];
  const float* bk = (const float*)d_in[5];
  const float* wv = (const float*)d_in[6];
  const float* bv = (const float*)d_in[7];
  const float* wo = (const float*)d_in[8];
  const float* bo = (const float*)d_in[9];
  float* out = (float*)d_out;

  char* ws = (char*)d_ws;
  const size_t MiB = 1048576;

  f16* qh  = (f16*)(ws + 56 * MiB);            // 16
  f16* ql  = (f16*)(ws + 72 * MiB);            // 16
  f16* kh  = (f16*)(ws + 88 * MiB);            // 8
  f16* kl  = (f16*)(ws + 96 * MiB);            // 8
  float* v = (float*)(ws + 104 * MiB);         // 16 (f32)
  f16* ao  = (f16*)(ws + 120 * MiB);           // 16
  f16* wqh = (f16*)(ws + 136 * MiB);
  f16* wql = (f16*)(ws + 136 * MiB + 524288);
  f16* wkh = (f16*)(ws + 137 * MiB);
  f16* wkl = (f16*)(ws + 137 * MiB + 786432);
  f16* wvh = (f16*)(ws + 138 * MiB + 524288);
  f16* wvl = (f16*)(ws + 139 * MiB + 262144);
  f16* woh = (f16*)(ws + 140 * MiB);
  f16* wol = (f16*)(ws + 140 * MiB + 524288);

  dim3 blk(256);
  const float WS = 2048.0f, IWS = 1.0f / 2048.0f;

  // weight splits only (x and y splits fused into GEMM staging)
  split4<<<dim3(1280), blk, 0, stream>>>(wq, wqh, wql, 65536, WS,
                                         wk, wkh, wkl, 98304, WS,
                                         wv, wvh, wvl, 98304, 1.0f,
                                         wo, woh, wol, 65536, 1.0f);

  // Q-proj: A = x fp32, in-register split
  gemm_f16<3, 1, 1><<<dim3(4, 128), blk, 0, stream>>>(nullptr, nullptr, x,
      wqh, wql, bq, nullptr, qh, ql, 16384, 512, 512, IWS, 8.0f);
  // K-proj: A = y fp32, in-register split
  gemm_f16<3, 1, 1><<<dim3(4, 64), blk, 0, stream>>>(nullptr, nullptr, y,
      wkh, wkl, bk, nullptr, kh, kl, 8192, 512, 768, IWS, 64.0f);
  // V-proj: A = y fp32, in-register split (hi only)
  gemm_f16<1, 0, 1><<<dim3(4, 64), blk, 0, stream>>>(nullptr, nullptr, y,
      wvh, nullptr, bv, v, nullptr, nullptr, 8192, 512, 768, 1.0f, 1.0f);

  attn_v14<<<dim3(1024), blk, 0, stream>>>(qh, ql, kh, kl, v, ao);

  // O-proj
  gemm_f16<1, 0, 0><<<dim3(4, 128), blk, 0, stream>>>(ao, nullptr, nullptr,
      woh, nullptr, bo, out, nullptr, nullptr, 16384, 512, 512, 1.0f, 1.0f);
}